// Round 1
// baseline (329.823 us; speedup 1.0000x reference)
//
#include <hip/hip_runtime.h>
#include <math.h>

#define B_N 256
#define GHW 100

__device__ __forceinline__ float sigmf(float x) { return 1.f / (1.f + __expf(-x)); }

// Compose linear MLP: M[j][k] = sum_m w2[j][m]*w1[m][k]; c[j] = b2[j] + sum_m w2[j][m]*b1[m]
__global__ void mlp_compose(const float* __restrict__ w1, const float* __restrict__ b1,
                            const float* __restrict__ w2, const float* __restrict__ b2,
                            float* __restrict__ Mc) {
    int tid = threadIdx.x;              // 128 threads
    int j = tid >> 5, k = tid & 31;     // j<4, k<32
    float acc = 0.f;
    for (int m = 0; m < 512; ++m) acc = fmaf(w2[j*512 + m], w1[m*32 + k], acc);
    Mc[j*32 + k] = acc;
    if (tid < 4) {
        float c = b2[tid];
        for (int m = 0; m < 512; ++m) c = fmaf(w2[tid*512 + m], b1[m], c);
        Mc[128 + tid] = c;
    }
}

// 32ch -> 32ch 2x2 conv on a small patch. wT layout: [cout][tap*32+cin], row stride 132.
// Patch positions with global coords >= 100 are zero (they are the next layer's padding).
template<int SIN, int SOUT>
__device__ __forceinline__ void conv32x32(const float* __restrict__ in, float* __restrict__ outp,
                                          const float* __restrict__ wT, const float* __restrict__ bias,
                                          int fy, int fx, int tid) {
    constexpr int N = SOUT * SOUT * 32;
    for (int o = tid; o < N; o += 256) {
        int c = o & 31, p = o >> 5;
        int py = p / SOUT, px = p - py * SOUT;
        float acc = 0.f;
        if (fy + py < GHW && fx + px < GHW) {
            acc = bias[c];
            const float* wr = wT + c * 132;
#pragma unroll
            for (int tap = 0; tap < 4; ++tap) {
                int ky = tap >> 1, kx = tap & 1;
                const float* ir = in + ((py + ky) * SIN + (px + kx)) * 32;
                const float* wt = wr + tap * 32;
#pragma unroll
                for (int ci = 0; ci < 32; ci += 4) {
                    float4 iv = *(const float4*)(ir + ci);
                    float4 wv = *(const float4*)(wt + ci);
                    acc = fmaf(iv.x, wv.x, acc);
                    acc = fmaf(iv.y, wv.y, acc);
                    acc = fmaf(iv.z, wv.z, acc);
                    acc = fmaf(iv.w, wv.w, acc);
                }
            }
            acc = fmaxf(acc, 0.f);
        }
        outp[p * 32 + c] = acc;
    }
}

__global__ __launch_bounds__(256) void r2p2_main(
    const float* __restrict__ z, const float* __restrict__ past, const float* __restrict__ lidar,
    const float* __restrict__ w0, const float* __restrict__ b0,
    const float* __restrict__ w1, const float* __restrict__ b1,
    const float* __restrict__ w2, const float* __restrict__ b2,
    const float* __restrict__ w3, const float* __restrict__ b3,
    const float* __restrict__ enc_wih, const float* __restrict__ enc_whh,
    const float* __restrict__ enc_bih, const float* __restrict__ enc_bhh,
    const float* __restrict__ dec_wih, const float* __restrict__ dec_whh,
    const float* __restrict__ dec_bih, const float* __restrict__ dec_bhh,
    const float* __restrict__ Mc, float* __restrict__ out) {
    const int b = blockIdx.x;
    const int tid = threadIdx.x;

    __shared__ float s[15360];               // 60 KB
    float* W0  = s;            // 256   [tap*2+cin][cout]
    float* B0  = s + 256;      // 32
    float* W1T = s + 288;      // 4224 = 32 x 132
    float* W2T = s + 4512;     // 4224
    float* W3T = s + 8736;     // 4224
    float* B1  = s + 12960;    // 32
    float* B2  = s + 12992;    // 32
    float* B3  = s + 13024;    // 32
    float* LID = s + 13056;    // 72   (6x6x2)
    float* C0  = s + 13128;    // 800  (5x5x32)
    float* C1  = s + 13928;    // 512  (4x4x32)
    float* C2  = s + 14440;    // 288  (3x3x32)
    float* C3  = s + 14728;    // 128  (2x2x32)
    float* XV  = s + 14856;    // 34 (+2 pad)
    float* HV  = s + 14892;    // 32
    float* GI  = s + 14924;    // 96
    float* GH  = s + 15020;    // 96
    float* LS  = s + 15116;    // 4
    float* YB  = s + 15120;    // 4  (y1[2], y2[2])
    float* PAST= s + 15124;    // 40
    float* ZV  = s + 15164;    // 60  -> 15224

    // ---- stage weights ----
    for (int i = tid; i < 256; i += 256) W0[i] = w0[i];
    if (tid < 32) { B0[tid] = b0[tid]; B1[tid] = b1[tid]; B2[tid] = b2[tid]; B3[tid] = b3[tid]; }
    for (int i = tid; i < 4096; i += 256) {
        int c = i & 31, tc = i >> 5;  // tc = tap*32+cin
        W1T[c * 132 + tc] = w1[i];
        W2T[c * 132 + tc] = w2[i];
        W3T[c * 132 + tc] = w3[i];
    }
    for (int i = tid; i < 40; i += 256) PAST[i] = past[b * 40 + i];
    for (int i = tid; i < 60; i += 256) ZV[i] = z[b * 60 + i];
    if (tid < 32) HV[tid] = 0.f;
    if (tid == 0) {
        YB[0] = past[b * 40 + 38]; YB[1] = past[b * 40 + 39];  // y_tm1 = past[19]
        YB[2] = past[b * 40 + 36]; YB[3] = past[b * 40 + 37];  // y_tm2 = past[18]
    }

    // GRU/MLP weight rows in registers
    float dwih[34], dwhh[32], dbih = 0.f, dbhh = 0.f;
    float ewih0 = 0.f, ewih1 = 0.f, ewhh[32], ebih = 0.f, ebhh = 0.f;
    if (tid < 96) {
#pragma unroll
        for (int k = 0; k < 34; ++k) dwih[k] = dec_wih[tid * 34 + k];
#pragma unroll
        for (int k = 0; k < 32; ++k) dwhh[k] = dec_whh[tid * 32 + k];
        dbih = dec_bih[tid]; dbhh = dec_bhh[tid];
        ewih0 = enc_wih[tid * 2]; ewih1 = enc_wih[tid * 2 + 1];
#pragma unroll
        for (int k = 0; k < 32; ++k) ewhh[k] = enc_whh[tid * 32 + k];
        ebih = enc_bih[tid]; ebhh = enc_bhh[tid];
    }
    float mrow[32], mc = 0.f;
    if (tid < 4) {
#pragma unroll
        for (int k = 0; k < 32; ++k) mrow[k] = Mc[tid * 32 + k];
        mc = Mc[128 + tid];
    }
    __syncthreads();

    // ---- GRU encoder over 20 past steps ----
    for (int t = 0; t < 20; ++t) {
        if (tid < 96) {
            float x0 = PAST[t * 2], x1 = PAST[t * 2 + 1];
            float gi = fmaf(x1, ewih1, fmaf(x0, ewih0, ebih));
            float gh = ebhh;
#pragma unroll
            for (int k = 0; k < 32; ++k) gh = fmaf(HV[k], ewhh[k], gh);
            GI[tid] = gi; GH[tid] = gh;
        }
        __syncthreads();
        if (tid < 32) {
            float r  = sigmf(GI[tid] + GH[tid]);
            float zg = sigmf(GI[32 + tid] + GH[32 + tid]);
            float n  = tanhf(fmaf(r, GH[64 + tid], GI[64 + tid]));
            HV[tid] = fmaf(zg, HV[tid], (1.f - zg) * n);
        }
        __syncthreads();
    }

    // ---- autoregressive decoder, 30 steps ----
    const float* lb = lidar + (size_t)b * (GHW * GHW * 2);
    float la = 0.f;
    for (int t = 0; t < 30; ++t) {
        float q0 = YB[0], q1 = YB[1];
        float f0 = fminf(fmaxf(floorf(q0), 0.f), 98.f);
        float f1 = fminf(fmaxf(floorf(q1), 0.f), 98.f);
        int fy = (int)f0, fx = (int)f1;
        float ay = fminf(fmaxf(q0 - f0, 0.f), 1.f);
        float ax = fminf(fmaxf(q1 - f1, 0.f), 1.f);

        // 6x6x2 lidar patch (zero-padded past grid edge)
        for (int i = tid; i < 72; i += 256) {
            int ch = i & 1, pp = i >> 1;
            int py = pp / 6, px = pp - py * 6;
            int gy = fy + py, gx = fx + px;
            LID[i] = (gy < GHW && gx < GHW) ? lb[(gy * GHW + gx) * 2 + ch] : 0.f;
        }
        __syncthreads();

        // conv0: 2ch -> 32ch, 5x5 out
        for (int o = tid; o < 800; o += 256) {
            int c = o & 31, p = o >> 5;
            int py = p / 5, px = p - py * 5;
            float acc = 0.f;
            if (fy + py < GHW && fx + px < GHW) {
                acc = B0[c];
#pragma unroll
                for (int tap = 0; tap < 4; ++tap) {
                    int ky = tap >> 1, kx = tap & 1;
                    const float* ir = LID + ((py + ky) * 6 + (px + kx)) * 2;
                    acc = fmaf(ir[0], W0[(tap * 2 + 0) * 32 + c], acc);
                    acc = fmaf(ir[1], W0[(tap * 2 + 1) * 32 + c], acc);
                }
                acc = fmaxf(acc, 0.f);
            }
            C0[p * 32 + c] = acc;
        }
        __syncthreads();
        conv32x32<5, 4>(C0, C1, W1T, B1, fy, fx, tid);
        __syncthreads();
        conv32x32<4, 3>(C1, C2, W2T, B2, fy, fx, tid);
        __syncthreads();
        conv32x32<3, 2>(C2, C3, W3T, B3, fy, fx, tid);
        __syncthreads();

        // bilinear + build x = [y1, interp]
        if (tid < 32) {
            float tl = C3[tid], tr = C3[32 + tid], bl = C3[64 + tid], br = C3[96 + tid];
            float top = fmaf(ax, tr - tl, tl);
            float bot = fmaf(ax, br - bl, bl);
            XV[2 + tid] = fmaf(ay, bot - top, top);
        }
        if (tid == 32) { XV[0] = q0; XV[1] = q1; }
        __syncthreads();

        // decoder GRU gates
        if (tid < 96) {
            float gi = dbih;
#pragma unroll
            for (int k = 0; k < 34; ++k) gi = fmaf(XV[k], dwih[k], gi);
            float gh = dbhh;
#pragma unroll
            for (int k = 0; k < 32; ++k) gh = fmaf(HV[k], dwhh[k], gh);
            GI[tid] = gi; GH[tid] = gh;
        }
        __syncthreads();
        if (tid < 32) {
            float r  = sigmf(GI[tid] + GH[tid]);
            float zg = sigmf(GI[32 + tid] + GH[32 + tid]);
            float n  = tanhf(fmaf(r, GH[64 + tid], GI[64 + tid]));
            HV[tid] = fmaf(zg, HV[tid], (1.f - zg) * n);
        }
        __syncthreads();

        // composed MLP: ls = h @ M^T + c
        if (tid < 4) {
            float acc = mc;
#pragma unroll
            for (int k = 0; k < 32; ++k) acc = fmaf(HV[k], mrow[k], acc);
            LS[tid] = acc;
        }
        __syncthreads();

        if (tid == 0) {
            float s0 = fmaxf(LS[2], 0.f) + log1pf(__expf(-fabsf(LS[2])));
            float s1 = fmaxf(LS[3], 0.f) + log1pf(__expf(-fabsf(LS[3])));
            float zt0 = ZV[t * 2], zt1 = ZV[t * 2 + 1];
            float y0 = 2.f * q0 - YB[2] + LS[0] + s0 * zt0;
            float y1 = 2.f * q1 - YB[3] + LS[1] + s1 * zt1;
            out[b * 60 + t * 2]     = y0;
            out[b * 60 + t * 2 + 1] = y1;
            la += __logf(s0) + __logf(s1);
            YB[2] = q0; YB[3] = q1; YB[0] = y0; YB[1] = y1;
        }
        __syncthreads();
    }
    if (tid == 0) out[B_N * 60 + b] = la;
}

extern "C" void kernel_launch(void* const* d_in, const int* in_sizes, int n_in,
                              void* d_out, int out_size, void* d_ws, size_t ws_size,
                              hipStream_t stream) {
    const float* z    = (const float*)d_in[0];
    const float* past = (const float*)d_in[1];
    const float* lid  = (const float*)d_in[2];
    const float* c0w = (const float*)d_in[3];  const float* c0b = (const float*)d_in[4];
    const float* c1w = (const float*)d_in[5];  const float* c1b = (const float*)d_in[6];
    const float* c2w = (const float*)d_in[7];  const float* c2b = (const float*)d_in[8];
    const float* c3w = (const float*)d_in[9];  const float* c3b = (const float*)d_in[10];
    const float* ewih = (const float*)d_in[11]; const float* ewhh = (const float*)d_in[12];
    const float* ebih = (const float*)d_in[13]; const float* ebhh = (const float*)d_in[14];
    const float* dwih = (const float*)d_in[15]; const float* dwhh = (const float*)d_in[16];
    const float* dbih = (const float*)d_in[17]; const float* dbhh = (const float*)d_in[18];
    const float* mw1 = (const float*)d_in[19]; const float* mb1 = (const float*)d_in[20];
    const float* mw2 = (const float*)d_in[21]; const float* mb2 = (const float*)d_in[22];
    float* out = (float*)d_out;
    float* Mc  = (float*)d_ws;   // 132 floats

    mlp_compose<<<1, 128, 0, stream>>>(mw1, mb1, mw2, mb2, Mc);
    r2p2_main<<<256, 256, 0, stream>>>(z, past, lid, c0w, c0b, c1w, c1b, c2w, c2b, c3w, c3b,
                                       ewih, ewhh, ebih, ebhh, dwih, dwhh, dbih, dbhh, Mc, out);
}

// Round 2
// 247.992 us; speedup vs baseline: 1.3300x; 1.3300x over previous
//
#include <hip/hip_runtime.h>
#include <math.h>

typedef __attribute__((ext_vector_type(8))) short  short8;
typedef __attribute__((ext_vector_type(4))) float  f32x4;
typedef __attribute__((ext_vector_type(4))) unsigned int uint4v;

#define WSYNC() asm volatile("s_waitcnt lgkmcnt(0)" ::: "memory")

__device__ __forceinline__ float sigmf(float x) { return 1.f / (1.f + __expf(-x)); }
__device__ __forceinline__ unsigned short f2bf(float f) {
    unsigned u = __builtin_bit_cast(unsigned, f);
    u = u + 0x7fffu + ((u >> 16) & 1u);
    return (unsigned short)(u >> 16);
}
__device__ __forceinline__ float bf2f(unsigned short s) {
    unsigned u = ((unsigned)s) << 16;
    return __builtin_bit_cast(float, u);
}
__device__ __forceinline__ f32x4 mfma16(short8 a, short8 b, f32x4 c) {
    return __builtin_amdgcn_mfma_f32_16x16x32_bf16(a, b, c, 0, 0, 0);
}

// pack 4 accumulator values (+bias, relu, oob-zero, bf16) into one 8B LDS write
__device__ __forceinline__ void store4(short* dst, f32x4 acc, f32x4 bias, bool oob) {
    float v0 = oob ? 0.f : fmaxf(acc[0] + bias[0], 0.f);
    float v1 = oob ? 0.f : fmaxf(acc[1] + bias[1], 0.f);
    float v2 = oob ? 0.f : fmaxf(acc[2] + bias[2], 0.f);
    float v3 = oob ? 0.f : fmaxf(acc[3] + bias[3], 0.f);
    uint2 u;
    u.x = (unsigned)f2bf(v0) | ((unsigned)f2bf(v1) << 16);
    u.y = (unsigned)f2bf(v2) | ((unsigned)f2bf(v3) << 16);
    *(uint2*)dst = u;
}

__global__ __launch_bounds__(256, 1) void r2p2_fused(
    const float* __restrict__ z, const float* __restrict__ past, const float* __restrict__ lidar,
    const float* __restrict__ w0, const float* __restrict__ b0,
    const float* __restrict__ w1, const float* __restrict__ b1,
    const float* __restrict__ w2, const float* __restrict__ b2,
    const float* __restrict__ w3, const float* __restrict__ b3,
    const float* __restrict__ enc_wih, const float* __restrict__ enc_whh,
    const float* __restrict__ enc_bih, const float* __restrict__ enc_bhh,
    const float* __restrict__ dec_wih, const float* __restrict__ dec_whh,
    const float* __restrict__ dec_bih, const float* __restrict__ dec_bhh,
    const float* __restrict__ mw1, const float* __restrict__ mb1,
    const float* __restrict__ mw2, const float* __restrict__ mb2,
    float* __restrict__ out) {

    const int tid = threadIdx.x;
    const int b   = blockIdx.x;

    __shared__ unsigned int sLIDu[10000];   // [gy*100+gx] -> 2 packed bf16 (ch0|ch1<<16)
    __shared__ short C0s[25 * 32];          // [pixel][cout] bf16
    __shared__ short C1s[16 * 32];
    __shared__ short C2s[9 * 32];
    __shared__ short C3s[4 * 32];
    __shared__ float XVs[34];
    __shared__ float HVs[32];
    __shared__ float ZVs[60];
    __shared__ float MMs[132];              // composed MLP: M[4][32] + c[4]

    // ================= waves 1-3: stage lidar (f32->bf16), z, compose MLP ======
    if (tid >= 64) {
        int st = tid - 64;                  // 0..191
        const float2* lp = (const float2*)(lidar + (size_t)b * 20000);
        for (int i = st; i < 10000; i += 192) {
            float2 v = lp[i];
            sLIDu[i] = (unsigned)f2bf(v.x) | ((unsigned)f2bf(v.y) << 16);
        }
        if (tid >= 192 && tid < 252) ZVs[tid - 192] = z[b * 60 + (tid - 192)];
        if (st < 128) {                     // composed MLP  M = W2@W1
            int j = st >> 5, k = st & 31;
            float acc = 0.f;
            for (int m = 0; m < 512; ++m) acc = fmaf(mw2[j * 512 + m], mw1[m * 32 + k], acc);
            MMs[j * 32 + k] = acc;
            if (st < 4) {
                float c = mb2[st];
                for (int m = 0; m < 512; ++m) c = fmaf(mw2[st * 512 + m], mb1[m], c);
                MMs[128 + st] = c;
            }
        }
    } else {
        // ================= wave 0: prepack A-frags + encoder ====================
        const int lane = tid, n = tid & 15, q = tid >> 4;

        // A-fragment layout (16x16x32 bf16): lane holds A[m=lane&15][k=q*8+j]
        short8 A0[2]; short8 A1[2][4], A2[2][4], A3[2][4];
        f32x4 bs0[2], bs1[2], bs2[2], bs3[2];
#pragma unroll
        for (int mt = 0; mt < 2; ++mt) {
#pragma unroll
            for (int j = 0; j < 8; ++j)     // conv0: real K = 8 (4 taps x 2ch), rest 0
                A0[mt][j] = (q == 0) ? (short)f2bf(w0[j * 32 + mt * 16 + n]) : (short)0;
#pragma unroll
            for (int r = 0; r < 4; ++r) {
                bs0[mt][r] = b0[mt * 16 + q * 4 + r];
                bs1[mt][r] = b1[mt * 16 + q * 4 + r];
                bs2[mt][r] = b2[mt * 16 + q * 4 + r];
                bs3[mt][r] = b3[mt * 16 + q * 4 + r];
            }
#pragma unroll
            for (int ks = 0; ks < 4; ++ks)
#pragma unroll
                for (int j = 0; j < 8; ++j) {
                    int k = ks * 32 + q * 8 + j;
                    A1[mt][ks][j] = (short)f2bf(w1[k * 32 + mt * 16 + n]);
                    A2[mt][ks][j] = (short)f2bf(w2[k * 32 + mt * 16 + n]);
                    A3[mt][ks][j] = (short)f2bf(w3[k * 32 + mt * 16 + n]);
                }
        }

        if (lane < 32) HVs[lane] = 0.f;
        WSYNC();

        // ---- GRU encoder, 20 steps, single wave ----
        for (int t = 0; t < 20; ++t) {
            float x0 = past[b * 40 + 2 * t], x1 = past[b * 40 + 2 * t + 1];
            float g1 = enc_bih[lane] + enc_bhh[lane]
                     + x0 * enc_wih[2 * lane] + x1 * enc_wih[2 * lane + 1];
#pragma unroll
            for (int k = 0; k < 32; ++k) g1 = fmaf(HVs[k], enc_whh[lane * 32 + k], g1);
            float rz = sigmf(g1);
            float p2;
            if (lane < 32) {
                int g = 64 + lane;
                p2 = enc_bih[g] + x0 * enc_wih[2 * g] + x1 * enc_wih[2 * g + 1];
            } else {
                int g = 64 + (lane - 32);
                p2 = enc_bhh[g];
#pragma unroll
                for (int k = 0; k < 32; ++k) p2 = fmaf(HVs[k], enc_whh[g * 32 + k], p2);
            }
            float ghn = __shfl_xor(p2, 32, 64);
            float zz  = __shfl_xor(rz, 32, 64);
            if (lane < 32) {
                float nn = tanhf(fmaf(rz, ghn, p2));
                float h  = HVs[lane];
                HVs[lane] = fmaf(zz, h, (1.f - zz) * nn);
            }
            WSYNC();
        }

        __syncthreads();                    // join: lidar/ZVs/MMs staged, h_enc ready

        // MLP rows -> regs (lanes 0-3)
        float mrow[32], mcc = 0.f;
        if (lane < 4) {
#pragma unroll
            for (int k = 0; k < 32; ++k) mrow[k] = MMs[lane * 32 + k];
            mcc = MMs[128 + lane];
        }

        // ================= autoregressive decoder, single wave, no barriers ====
        float q0 = past[b * 40 + 38], q1 = past[b * 40 + 39];
        float p0 = past[b * 40 + 36], p1 = past[b * 40 + 37];
        float la = 0.f;

        for (int t = 0; t < 30; ++t) {
            float f0 = fminf(fmaxf(floorf(q0), 0.f), 98.f);
            float f1 = fminf(fmaxf(floorf(q1), 0.f), 98.f);
            int   fy = (int)f0, fx = (int)f1;
            float ay = fminf(fmaxf(q0 - f0, 0.f), 1.f);
            float ax = fminf(fmaxf(q1 - f1, 0.f), 1.f);

            // ---- conv0 via MFMA: 2 n-tiles over 25 positions ----
#pragma unroll
            for (int nt = 0; nt < 2; ++nt) {
                int pos = nt * 16 + n;
                int pe  = (pos < 25) ? pos : 24;
                int py = pe / 5, px = pe % 5;
                uint4v wv = {0u, 0u, 0u, 0u};
                if (q == 0 && pos < 25) {
#pragma unroll
                    for (int tp = 0; tp < 4; ++tp) {
                        int gy = fy + py + (tp >> 1), gx = fx + px + (tp & 1);
                        wv[tp] = (gy < 100 && gx < 100) ? sLIDu[gy * 100 + gx] : 0u;
                    }
                }
                short8 bf = __builtin_bit_cast(short8, wv);
                f32x4 acc0 = {0.f, 0.f, 0.f, 0.f}, acc1 = {0.f, 0.f, 0.f, 0.f};
                acc0 = mfma16(A0[0], bf, acc0);
                acc1 = mfma16(A0[1], bf, acc1);
                if (pos < 25) {
                    bool oob = (fy + py >= 100) || (fx + px >= 100);
                    store4(&C0s[pe * 32 + q * 4],      acc0, bs0[0], oob);
                    store4(&C0s[pe * 32 + 16 + q * 4], acc1, bs0[1], oob);
                }
            }
            WSYNC();

            // ---- conv1: 5x5 -> 4x4 ----
            {
                int py = n >> 2, px = n & 3;
                f32x4 acc0 = {0.f, 0.f, 0.f, 0.f}, acc1 = {0.f, 0.f, 0.f, 0.f};
#pragma unroll
                for (int ks = 0; ks < 4; ++ks) {
                    int pix = (py + (ks >> 1)) * 5 + (px + (ks & 1));
                    short8 bf = *(const short8*)(C0s + pix * 32 + q * 8);
                    acc0 = mfma16(A1[0][ks], bf, acc0);
                    acc1 = mfma16(A1[1][ks], bf, acc1);
                }
                WSYNC();   // all reads of C0s done before C1s writes land (aliasing safety)
                bool oob = (fy + py >= 100) || (fx + px >= 100);
                store4(&C1s[n * 32 + q * 4],      acc0, bs1[0], oob);
                store4(&C1s[n * 32 + 16 + q * 4], acc1, bs1[1], oob);
            }
            WSYNC();

            // ---- conv2: 4x4 -> 3x3 ----
            {
                int pe = (n < 9) ? n : 8;
                int py = pe / 3, px = pe % 3;
                f32x4 acc0 = {0.f, 0.f, 0.f, 0.f}, acc1 = {0.f, 0.f, 0.f, 0.f};
#pragma unroll
                for (int ks = 0; ks < 4; ++ks) {
                    int pix = (py + (ks >> 1)) * 4 + (px + (ks & 1));
                    short8 bf = *(const short8*)(C1s + pix * 32 + q * 8);
                    acc0 = mfma16(A2[0][ks], bf, acc0);
                    acc1 = mfma16(A2[1][ks], bf, acc1);
                }
                WSYNC();
                if (n < 9) {
                    bool oob = (fy + py >= 100) || (fx + px >= 100);
                    store4(&C2s[pe * 32 + q * 4],      acc0, bs2[0], oob);
                    store4(&C2s[pe * 32 + 16 + q * 4], acc1, bs2[1], oob);
                }
            }
            WSYNC();

            // ---- conv3: 3x3 -> 2x2 ----
            {
                int pe = (n < 4) ? n : 3;
                int py = pe >> 1, px = pe & 1;
                f32x4 acc0 = {0.f, 0.f, 0.f, 0.f}, acc1 = {0.f, 0.f, 0.f, 0.f};
#pragma unroll
                for (int ks = 0; ks < 4; ++ks) {
                    int pix = (py + (ks >> 1)) * 3 + (px + (ks & 1));
                    short8 bf = *(const short8*)(C2s + pix * 32 + q * 8);
                    acc0 = mfma16(A3[0][ks], bf, acc0);
                    acc1 = mfma16(A3[1][ks], bf, acc1);
                }
                WSYNC();
                if (n < 4) {
                    bool oob = (fy + py >= 100) || (fx + px >= 100);
                    store4(&C3s[pe * 32 + q * 4],      acc0, bs3[0], oob);
                    store4(&C3s[pe * 32 + 16 + q * 4], acc1, bs3[1], oob);
                }
            }
            WSYNC();

            // ---- bilinear sample -> x = [y1, interp] ----
            if (lane < 32) {
                float tl = bf2f((unsigned short)C3s[lane]);
                float tr = bf2f((unsigned short)C3s[32 + lane]);
                float bl = bf2f((unsigned short)C3s[64 + lane]);
                float br = bf2f((unsigned short)C3s[96 + lane]);
                float top = fmaf(ax, tr - tl, tl);
                float bot = fmaf(ax, br - bl, bl);
                XVs[2 + lane] = fmaf(ay, bot - top, top);
            }
            if (lane == 0) { XVs[0] = q0; XVs[1] = q1; }
            WSYNC();

            // ---- decoder GRU: pass1 = r,z gates (64 lanes); pass2 = n-gate halves ----
            float g1 = dec_bih[lane] + dec_bhh[lane];
#pragma unroll
            for (int k = 0; k < 34; ++k) g1 = fmaf(XVs[k], dec_wih[lane * 34 + k], g1);
#pragma unroll
            for (int k = 0; k < 32; ++k) g1 = fmaf(HVs[k], dec_whh[lane * 32 + k], g1);
            float rz = sigmf(g1);
            float p2;
            if (lane < 32) {
                int g = 64 + lane;
                p2 = dec_bih[g];
#pragma unroll
                for (int k = 0; k < 34; ++k) p2 = fmaf(XVs[k], dec_wih[g * 34 + k], p2);
            } else {
                int g = 64 + (lane - 32);
                p2 = dec_bhh[g];
#pragma unroll
                for (int k = 0; k < 32; ++k) p2 = fmaf(HVs[k], dec_whh[g * 32 + k], p2);
            }
            float ghn = __shfl_xor(p2, 32, 64);
            float zz  = __shfl_xor(rz, 32, 64);
            if (lane < 32) {
                float nn = tanhf(fmaf(rz, ghn, p2));
                float h  = HVs[lane];
                HVs[lane] = fmaf(zz, h, (1.f - zz) * nn);
            }
            WSYNC();

            // ---- composed MLP head (lanes 0-3) + broadcast ----
            float ls = 0.f;
            if (lane < 4) {
                ls = mcc;
#pragma unroll
                for (int k = 0; k < 32; ++k) ls = fmaf(HVs[k], mrow[k], ls);
            }
            float l0 = __shfl(ls, 0, 64), l1 = __shfl(ls, 1, 64);
            float l2 = __shfl(ls, 2, 64), l3 = __shfl(ls, 3, 64);

            float s0 = fmaxf(l2, 0.f) + log1pf(__expf(-fabsf(l2)));
            float s1 = fmaxf(l3, 0.f) + log1pf(__expf(-fabsf(l3)));
            float zt0 = ZVs[2 * t], zt1 = ZVs[2 * t + 1];
            float ny0 = 2.f * q0 - p0 + l0 + s0 * zt0;
            float ny1 = 2.f * q1 - p1 + l1 + s1 * zt1;
            if (lane == 0) {
                out[b * 60 + 2 * t]     = ny0;
                out[b * 60 + 2 * t + 1] = ny1;
            }
            la += __logf(s0) + __logf(s1);
            p0 = q0; p1 = q1; q0 = ny0; q1 = ny1;
        }
        if (lane == 0) out[256 * 60 + b] = la;
        return;
    }
    __syncthreads();   // staging waves join wave0's barrier, then exit
}

extern "C" void kernel_launch(void* const* d_in, const int* in_sizes, int n_in,
                              void* d_out, int out_size, void* d_ws, size_t ws_size,
                              hipStream_t stream) {
    const float* z    = (const float*)d_in[0];
    const float* past = (const float*)d_in[1];
    const float* lid  = (const float*)d_in[2];
    const float* c0w = (const float*)d_in[3];  const float* c0b = (const float*)d_in[4];
    const float* c1w = (const float*)d_in[5];  const float* c1b = (const float*)d_in[6];
    const float* c2w = (const float*)d_in[7];  const float* c2b = (const float*)d_in[8];
    const float* c3w = (const float*)d_in[9];  const float* c3b = (const float*)d_in[10];
    const float* ewih = (const float*)d_in[11]; const float* ewhh = (const float*)d_in[12];
    const float* ebih = (const float*)d_in[13]; const float* ebhh = (const float*)d_in[14];
    const float* dwih = (const float*)d_in[15]; const float* dwhh = (const float*)d_in[16];
    const float* dbih = (const float*)d_in[17]; const float* dbhh = (const float*)d_in[18];
    const float* mw1 = (const float*)d_in[19]; const float* mb1 = (const float*)d_in[20];
    const float* mw2 = (const float*)d_in[21]; const float* mb2 = (const float*)d_in[22];
    float* out = (float*)d_out;

    r2p2_fused<<<256, 256, 0, stream>>>(z, past, lid, c0w, c0b, c1w, c1b, c2w, c2b, c3w, c3b,
                                        ewih, ewhh, ebih, ebhh, dwih, dwhh, dbih, dbhh,
                                        mw1, mb1, mw2, mb2, out);
}

// Round 3
// 219.799 us; speedup vs baseline: 1.5006x; 1.1283x over previous
//
#include <hip/hip_runtime.h>
#include <math.h>

typedef __attribute__((ext_vector_type(8))) short    short8;
typedef __attribute__((ext_vector_type(4))) float    f32x4;
typedef __attribute__((ext_vector_type(4))) unsigned uint4v;

#define WSYNC() asm volatile("s_waitcnt lgkmcnt(0)" ::: "memory")

__device__ __forceinline__ float sigmf(float x) { return 1.f / (1.f + __expf(-x)); }
__device__ __forceinline__ unsigned short f2bf(float f) {   // RNE
    unsigned u = __builtin_bit_cast(unsigned, f);
    u = u + 0x7fffu + ((u >> 16) & 1u);
    return (unsigned short)(u >> 16);
}
__device__ __forceinline__ unsigned pack_trunc(float hi, float lo) {  // 1 v_perm: bf16(lo) | bf16(hi)<<16 (truncate)
    return __builtin_amdgcn_perm(__builtin_bit_cast(unsigned, hi),
                                 __builtin_bit_cast(unsigned, lo), 0x07060302u);
}
__device__ __forceinline__ float rfl(float x) {
    return __builtin_bit_cast(float, __builtin_amdgcn_readfirstlane(__builtin_bit_cast(int, x)));
}
__device__ __forceinline__ f32x4 mfma16(short8 a, short8 b, f32x4 c) {
    return __builtin_amdgcn_mfma_f32_16x16x32_bf16(a, b, c, 0, 0, 0);
}
#define SWZ1(v) __builtin_bit_cast(float, __builtin_amdgcn_ds_swizzle(__builtin_bit_cast(int, v), 0x041F))
#define SWZ2(v) __builtin_bit_cast(float, __builtin_amdgcn_ds_swizzle(__builtin_bit_cast(int, v), 0x081F))

// relu + bf16-trunc pack + oob-zero + 8B LDS store
__device__ __forceinline__ void stc(short* dst, f32x4 v, bool oob) {
    float a0 = fmaxf(v[0], 0.f), a1 = fmaxf(v[1], 0.f);
    float a2 = fmaxf(v[2], 0.f), a3 = fmaxf(v[3], 0.f);
    uint2 u;
    u.x = pack_trunc(a1, a0);
    u.y = pack_trunc(a3, a2);
    if (oob) { u.x = 0u; u.y = 0u; }
    *(uint2*)dst = u;
}

__global__ __launch_bounds__(256, 1) void r2p2_fused(
    const float* __restrict__ z, const float* __restrict__ past, const float* __restrict__ lidar,
    const float* __restrict__ w0, const float* __restrict__ b0,
    const float* __restrict__ w1, const float* __restrict__ b1,
    const float* __restrict__ w2, const float* __restrict__ b2,
    const float* __restrict__ w3, const float* __restrict__ b3,
    const float* __restrict__ enc_wih, const float* __restrict__ enc_whh,
    const float* __restrict__ enc_bih, const float* __restrict__ enc_bhh,
    const float* __restrict__ dec_wih, const float* __restrict__ dec_whh,
    const float* __restrict__ dec_bih, const float* __restrict__ dec_bhh,
    const float* __restrict__ mw1, const float* __restrict__ mb1,
    const float* __restrict__ mw2, const float* __restrict__ mb2,
    float* __restrict__ out) {

    const int tid = threadIdx.x, b = blockIdx.x;
    const int wid = tid >> 6, lane = tid & 63;
    const int n = lane & 15, q = lane >> 4;

    __shared__ __align__(16) unsigned sLID[104 * 104];   // bf16x2 lidar, zero border (43.3 KB)
    __shared__ __align__(16) short C0s[25 * 40];         // [pixel][ch] stride 40 (anti-conflict)
    __shared__ __align__(16) short C1s[16 * 40];
    __shared__ __align__(16) short C2s[9 * 40];
    __shared__ __align__(16) short XV2[40];              // x = [y0,y1,interp32] bf16
    __shared__ __align__(16) short HV2[32];              // h bf16 (B-frag source)
    __shared__ __align__(16) float HVf[32];              // h f32 handoff enc->dec
    __shared__ __align__(16) float G1[64];               // r,z pre-activations
    __shared__ __align__(16) float GNi[32], GNh[32];     // n-gate gi / gh
    __shared__ __align__(16) float PASTs[40];
    __shared__ __align__(16) float ZVs[64];
    __shared__ __align__(16) float MMs[132];             // composed MLP M[4][32] + c[4]

    // ---- wave0 persistent state (assigned pre-barrier, used post-barrier) ----
    short8 A0[2], A1f[2][4], A2f[2][4], A3f[2][4];
    short8 Adi[6][2], Adh[6];
    f32x4 bs0[2], bs1[2], bs2[2], bs3[2];
    float d1a = 0.f, d1b = 0.f, dni = 0.f, dnh = 0.f;

    if (wid == 0) {
        // ====== wave 0: prepack conv + decoder-GRU A-frags ======
#pragma unroll
        for (int mt = 0; mt < 2; ++mt) {
            short8 f = (short8)0;
            if (q == 0) {
#pragma unroll
                for (int j = 0; j < 8; ++j) f[j] = (short)f2bf(w0[j * 32 + mt * 16 + n]);
            }
            A0[mt] = f;
            bs0[mt] = *(const f32x4*)(b0 + mt * 16 + q * 4);
            bs1[mt] = *(const f32x4*)(b1 + mt * 16 + q * 4);
            bs2[mt] = *(const f32x4*)(b2 + mt * 16 + q * 4);
            bs3[mt] = *(const f32x4*)(b3 + mt * 16 + q * 4);
#pragma unroll
            for (int ks = 0; ks < 4; ++ks) {
                short8 f1, f2, f3;
#pragma unroll
                for (int j = 0; j < 8; ++j) {
                    int idx = (ks * 32 + q * 8 + j) * 32 + mt * 16 + n;
                    f1[j] = (short)f2bf(w1[idx]);
                    f2[j] = (short)f2bf(w2[idx]);
                    f3[j] = (short)f2bf(w3[idx]);
                }
                A1f[mt][ks] = f1; A2f[mt][ks] = f2; A3f[mt][ks] = f3;
            }
        }
#pragma unroll
        for (int mt = 0; mt < 6; ++mt) {
            int g = mt * 16 + n;
            short8 f0, fh;
#pragma unroll
            for (int jj = 0; jj < 4; ++jj) {
                float2 wa = *(const float2*)(dec_wih + g * 34 + q * 8 + jj * 2);
                f0[2 * jj] = (short)f2bf(wa.x); f0[2 * jj + 1] = (short)f2bf(wa.y);
                float2 wh = *(const float2*)(dec_whh + g * 32 + q * 8 + jj * 2);
                fh[2 * jj] = (short)f2bf(wh.x); fh[2 * jj + 1] = (short)f2bf(wh.y);
            }
            Adi[mt][0] = f0; Adh[mt] = fh;
            short8 fx1 = (short8)0;
            if (q == 0) {
                float2 wa = *(const float2*)(dec_wih + g * 34 + 32);
                fx1[0] = (short)f2bf(wa.x); fx1[1] = (short)f2bf(wa.y);
            }
            Adi[mt][1] = fx1;
        }
        if (lane < 32) {
            d1a = dec_bih[lane] + dec_bhh[lane];
            d1b = dec_bih[lane + 32] + dec_bhh[lane + 32];
            dni = dec_bih[64 + lane]; dnh = dec_bhh[64 + lane];
        }
    } else if (wid == 1) {
        // ====== wave 1: encoder (MFMA GRU), writes h to HVf/HV2 ======
        short8 Aei[6], Aeh[6];
#pragma unroll
        for (int mt = 0; mt < 6; ++mt) {
            int g = mt * 16 + n;
            short8 fi = (short8)0;
            if (q == 0) {
                float2 wv = *(const float2*)(enc_wih + g * 2);
                fi[0] = (short)f2bf(wv.x); fi[1] = (short)f2bf(wv.y);
            }
            Aei[mt] = fi;
            short8 fh;
#pragma unroll
            for (int jj = 0; jj < 4; ++jj) {
                float2 wv = *(const float2*)(enc_whh + g * 32 + q * 8 + jj * 2);
                fh[2 * jj] = (short)f2bf(wv.x); fh[2 * jj + 1] = (short)f2bf(wv.y);
            }
            Aeh[mt] = fh;
        }
        float e1a = 0.f, e1b = 0.f, eni = 0.f, enh = 0.f, h = 0.f;
        if (lane < 32) {
            e1a = enc_bih[lane] + enc_bhh[lane];
            e1b = enc_bih[lane + 32] + enc_bhh[lane + 32];
            eni = enc_bih[64 + lane]; enh = enc_bhh[64 + lane];
            HV2[lane] = (short)0;
        }
        if (lane < 20) *(float2*)&PASTs[2 * lane] = *(const float2*)(past + b * 40 + 2 * lane);
        WSYNC();
        f32x4 z4 = {0.f, 0.f, 0.f, 0.f};
#pragma unroll 1
        for (int t = 0; t < 20; ++t) {
            short8 hf = *(const short8*)(HV2 + q * 8);
            float2 xp = *(const float2*)&PASTs[2 * t];
            short8 xf = (short8)0;
            if (q == 0) { xf[0] = (short)f2bf(xp.x); xf[1] = (short)f2bf(xp.y); }
            f32x4 g[6];
#pragma unroll
            for (int mt = 0; mt < 6; ++mt) g[mt] = mfma16(Aei[mt], xf, z4);
#pragma unroll
            for (int mt = 0; mt < 4; ++mt) g[mt] = mfma16(Aeh[mt], hf, g[mt]);
            f32x4 gh4 = mfma16(Aeh[4], hf, z4);
            f32x4 gh5 = mfma16(Aeh[5], hf, z4);
            if (n == 0) {
#pragma unroll
                for (int mt = 0; mt < 4; ++mt) *(f32x4*)&G1[mt * 16 + q * 4] = g[mt];
                *(f32x4*)&GNi[q * 4] = g[4]; *(f32x4*)&GNi[16 + q * 4] = g[5];
                *(f32x4*)&GNh[q * 4] = gh4; *(f32x4*)&GNh[16 + q * 4] = gh5;
            }
            WSYNC();
            if (lane < 32) {
                float r  = sigmf(G1[lane] + e1a);
                float zz = sigmf(G1[lane + 32] + e1b);
                float nn = tanhf(fmaf(r, GNh[lane] + enh, GNi[lane] + eni));
                h = fmaf(zz, h - nn, nn);
                HV2[lane] = (short)f2bf(h);
            }
            WSYNC();
        }
        if (lane < 32) HVf[lane] = h;
    } else {
        // ====== waves 2-3: z, composed MLP, lidar->bf16 with zero border ======
        int st = tid - 128;  // 0..127
        if (st < 60) ZVs[st] = z[b * 60 + st];
        {
            int j = st >> 5, k = st & 31;
            float acc = 0.f;
            for (int m = 0; m < 512; ++m) acc = fmaf(mw2[j * 512 + m], mw1[m * 32 + k], acc);
            MMs[j * 32 + k] = acc;
            if (st < 4) {
                float c = mb2[st];
                for (int m = 0; m < 512; ++m) c = fmaf(mw2[st * 512 + m], mb1[m], c);
                MMs[128 + st] = c;
            }
        }
        const float2* lp = (const float2*)(lidar + (size_t)b * 20000);
        for (int i = st; i < 10816; i += 128) {
            int r = (int)(((unsigned long long)i * 40330ull) >> 22);  // i / 104
            int c = i - r * 104;
            unsigned v = 0u;
            if (r < 100 && c < 100) { float2 t2 = lp[r * 100 + c]; v = pack_trunc(t2.y, t2.x); }
            sLID[i] = v;
        }
    }

    __syncthreads();
    if (wid != 0) return;

    // ====== wave 0: autoregressive decode, zero barriers ======
    short8 Am = (short8)0;
    if (n < 4) {
        const float* mp = MMs + n * 32 + q * 8;
#pragma unroll
        for (int j = 0; j < 8; ++j) Am[j] = (short)f2bf(mp[j]);
    }
    f32x4 mcv = {0.f, 0.f, 0.f, 0.f};
    if (q == 0) mcv = *(const f32x4*)(MMs + 128);
    float h = (lane < 32) ? HVf[lane] : 0.f;
    short8 hf = *(const short8*)(HV2 + q * 8);
    float q0 = past[b * 40 + 38], q1 = past[b * 40 + 39];
    float p0 = past[b * 40 + 36], p1 = past[b * 40 + 37];
    float la = 0.f;

    // hoisted per-lane geometry
    int py0a = n / 5, px0a = n % 5;
    int pe0b = (16 + n < 25) ? 16 + n : 24;
    int py0b = pe0b / 5, px0b = pe0b % 5;
    int ofs0a[4], ofs0b[4];
#pragma unroll
    for (int tp = 0; tp < 4; ++tp) {
        ofs0a[tp] = (py0a + (tp >> 1)) * 104 + px0a + (tp & 1);
        ofs0b[tp] = (py0b + (tp >> 1)) * 104 + px0b + (tp & 1);
    }
    int py1 = n >> 2, px1 = n & 3;
    int pe2 = (n < 9) ? n : 8, py2 = pe2 / 3, px2 = pe2 % 3;
    int pe3 = (n < 4) ? n : 3, py3 = pe3 >> 1, px3 = pe3 & 1;
    int pix1[4], pix2[4], pix3[4];
#pragma unroll
    for (int ks = 0; ks < 4; ++ks) {
        pix1[ks] = ((py1 + (ks >> 1)) * 5 + px1 + (ks & 1)) * 40;
        pix2[ks] = ((py2 + (ks >> 1)) * 4 + px2 + (ks & 1)) * 40;
        pix3[ks] = ((py3 + (ks >> 1)) * 3 + px3 + (ks & 1)) * 40;
    }
    f32x4 z4 = {0.f, 0.f, 0.f, 0.f};

#pragma unroll 1
    for (int t = 0; t < 30; ++t) {
        float f0 = fminf(fmaxf(floorf(q0), 0.f), 98.f);
        float f1v = fminf(fmaxf(floorf(q1), 0.f), 98.f);
        int fy = (int)f0, fx = (int)f1v;
        float ay = fminf(fmaxf(q0 - f0, 0.f), 1.f);
        float ax = fminf(fmaxf(q1 - f1v, 0.f), 1.f);
        int base = fy * 104 + fx;

        // ---- conv0 (border-padded gather, 2 n-tiles) ----
        short8 bfa = (short8)0, bfb = (short8)0;
        if (q == 0) {
            uint4v ua, ub;
#pragma unroll
            for (int tp = 0; tp < 4; ++tp) { ua[tp] = sLID[base + ofs0a[tp]]; ub[tp] = sLID[base + ofs0b[tp]]; }
            bfa = __builtin_bit_cast(short8, ua);
            bfb = __builtin_bit_cast(short8, ub);
        }
        f32x4 c00 = mfma16(A0[0], bfa, bs0[0]);
        f32x4 c01 = mfma16(A0[1], bfa, bs0[1]);
        f32x4 c10 = mfma16(A0[0], bfb, bs0[0]);
        f32x4 c11 = mfma16(A0[1], bfb, bs0[1]);
        bool oa = (fy + py0a >= 100) || (fx + px0a >= 100);
        bool ob = (fy + py0b >= 100) || (fx + px0b >= 100);
        stc(C0s + n * 40 + q * 4, c00, oa);
        stc(C0s + n * 40 + 16 + q * 4, c01, oa);
        if (16 + n < 25) {
            stc(C0s + (16 + n) * 40 + q * 4, c10, ob);
            stc(C0s + (16 + n) * 40 + 16 + q * 4, c11, ob);
        }
        WSYNC();

        // ---- conv1 ----
        {
            short8 bb[4];
#pragma unroll
            for (int ks = 0; ks < 4; ++ks) bb[ks] = *(const short8*)(C0s + pix1[ks] + q * 8);
            f32x4 a0 = bs1[0], a1 = bs1[1];
#pragma unroll
            for (int ks = 0; ks < 4; ++ks) { a0 = mfma16(A1f[0][ks], bb[ks], a0); a1 = mfma16(A1f[1][ks], bb[ks], a1); }
            bool o1 = (fy + py1 >= 100) || (fx + px1 >= 100);
            stc(C1s + n * 40 + q * 4, a0, o1);
            stc(C1s + n * 40 + 16 + q * 4, a1, o1);
        }
        WSYNC();

        // ---- conv2 ----
        {
            short8 bb[4];
#pragma unroll
            for (int ks = 0; ks < 4; ++ks) bb[ks] = *(const short8*)(C1s + pix2[ks] + q * 8);
            f32x4 a0 = bs2[0], a1 = bs2[1];
#pragma unroll
            for (int ks = 0; ks < 4; ++ks) { a0 = mfma16(A2f[0][ks], bb[ks], a0); a1 = mfma16(A2f[1][ks], bb[ks], a1); }
            if (n < 9) {
                bool o2 = (fy + py2 >= 100) || (fx + px2 >= 100);
                stc(C2s + n * 40 + q * 4, a0, o2);
                stc(C2s + n * 40 + 16 + q * 4, a1, o2);
            }
        }
        WSYNC();

        // ---- conv3 (in-register) + bilinear via swizzle butterfly ----
        {
            short8 bb[4];
#pragma unroll
            for (int ks = 0; ks < 4; ++ks) bb[ks] = *(const short8*)(C2s + pix3[ks] + q * 8);
            f32x4 a0 = bs3[0], a1 = bs3[1];
#pragma unroll
            for (int ks = 0; ks < 4; ++ks) { a0 = mfma16(A3f[0][ks], bb[ks], a0); a1 = mfma16(A3f[1][ks], bb[ks], a1); }
            float wy = (n & 2) ? ay : 1.f - ay;
            float wx = (n & 1) ? ax : 1.f - ax;
            float w = wy * wx;
#pragma unroll
            for (int r = 0; r < 4; ++r) {
                a0[r] = fmaxf(a0[r], 0.f) * w;
                a1[r] = fmaxf(a1[r], 0.f) * w;
                a0[r] += SWZ1(a0[r]); a1[r] += SWZ1(a1[r]);
                a0[r] += SWZ2(a0[r]); a1[r] += SWZ2(a1[r]);
            }
            if (n == 0) {
                *(unsigned*)&XV2[2 + q * 4]  = pack_trunc(a0[1], a0[0]);
                *(unsigned*)&XV2[4 + q * 4]  = pack_trunc(a0[3], a0[2]);
                *(unsigned*)&XV2[18 + q * 4] = pack_trunc(a1[1], a1[0]);
                *(unsigned*)&XV2[20 + q * 4] = pack_trunc(a1[3], a1[2]);
            }
            if (lane == 0)
                *(unsigned*)&XV2[0] = (unsigned)f2bf(q0) | ((unsigned)f2bf(q1) << 16);
        }
        WSYNC();

        // ---- decoder GRU: 18 MFMAs, bias at consumer ----
        {
            short8 xf0 = *(const short8*)(XV2 + q * 8);
            short8 xf1 = (short8)0;
            if (q == 0) {
                unsigned u = *(const unsigned*)&XV2[32];
                xf1[0] = (short)(u & 0xffffu); xf1[1] = (short)(u >> 16);
            }
            f32x4 g[6];
#pragma unroll
            for (int mt = 0; mt < 6; ++mt) g[mt] = mfma16(Adi[mt][0], xf0, z4);
#pragma unroll
            for (int mt = 0; mt < 6; ++mt) g[mt] = mfma16(Adi[mt][1], xf1, g[mt]);
#pragma unroll
            for (int mt = 0; mt < 4; ++mt) g[mt] = mfma16(Adh[mt], hf, g[mt]);
            f32x4 gh4 = mfma16(Adh[4], hf, z4);
            f32x4 gh5 = mfma16(Adh[5], hf, z4);
            if (n == 0) {
#pragma unroll
                for (int mt = 0; mt < 4; ++mt) *(f32x4*)&G1[mt * 16 + q * 4] = g[mt];
                *(f32x4*)&GNi[q * 4] = g[4]; *(f32x4*)&GNi[16 + q * 4] = g[5];
                *(f32x4*)&GNh[q * 4] = gh4; *(f32x4*)&GNh[16 + q * 4] = gh5;
            }
        }
        WSYNC();
        if (lane < 32) {
            float r  = sigmf(G1[lane] + d1a);
            float zz = sigmf(G1[lane + 32] + d1b);
            float nn = tanhf(fmaf(r, GNh[lane] + dnh, GNi[lane] + dni));
            h = fmaf(zz, h - nn, nn);
            HV2[lane] = (short)f2bf(h);
        }
        WSYNC();
        hf = *(const short8*)(HV2 + q * 8);
        float2 zv = *(const float2*)&ZVs[2 * t];

        // ---- composed MLP head + tail ----
        f32x4 ls = mfma16(Am, hf, mcv);
        float l2 = ls[2], l3 = ls[3];
        float s0 = fmaxf(l2, 0.f) + log1pf(__expf(-fabsf(l2)));
        float s1 = fmaxf(l3, 0.f) + log1pf(__expf(-fabsf(l3)));
        float ny0 = 2.f * q0 - p0 + ls[0] + s0 * zv.x;
        float ny1 = 2.f * q1 - p1 + ls[1] + s1 * zv.y;
        if (lane == 0) {
            float2 o2v = {ny0, ny1};
            *(float2*)(out + b * 60 + 2 * t) = o2v;
        }
        la += __logf(s0 * s1);
        p0 = q0; p1 = q1;
        q0 = rfl(ny0); q1 = rfl(ny1);
    }
    if (lane == 0) out[256 * 60 + b] = la;
}

extern "C" void kernel_launch(void* const* d_in, const int* in_sizes, int n_in,
                              void* d_out, int out_size, void* d_ws, size_t ws_size,
                              hipStream_t stream) {
    const float* z    = (const float*)d_in[0];
    const float* past = (const float*)d_in[1];
    const float* lid  = (const float*)d_in[2];
    const float* c0w = (const float*)d_in[3];  const float* c0b = (const float*)d_in[4];
    const float* c1w = (const float*)d_in[5];  const float* c1b = (const float*)d_in[6];
    const float* c2w = (const float*)d_in[7];  const float* c2b = (const float*)d_in[8];
    const float* c3w = (const float*)d_in[9];  const float* c3b = (const float*)d_in[10];
    const float* ewih = (const float*)d_in[11]; const float* ewhh = (const float*)d_in[12];
    const float* ebih = (const float*)d_in[13]; const float* ebhh = (const float*)d_in[14];
    const float* dwih = (const float*)d_in[15]; const float* dwhh = (const float*)d_in[16];
    const float* dbih = (const float*)d_in[17]; const float* dbhh = (const float*)d_in[18];
    const float* mw1 = (const float*)d_in[19]; const float* mb1 = (const float*)d_in[20];
    const float* mw2 = (const float*)d_in[21]; const float* mb2 = (const float*)d_in[22];
    float* out = (float*)d_out;

    r2p2_fused<<<256, 256, 0, stream>>>(z, past, lid, c0w, c0b, c1w, c1b, c2w, c2b, c3w, c3b,
                                        ewih, ewhh, ebih, ebhh, dwih, dwhh, dbih, dbhh,
                                        mw1, mb1, mw2, mb2, out);
}

// Round 4
// 216.247 us; speedup vs baseline: 1.5252x; 1.0164x over previous
//
#include <hip/hip_runtime.h>
#include <math.h>

typedef __attribute__((ext_vector_type(8))) short    short8;
typedef __attribute__((ext_vector_type(4))) float    f32x4;
typedef __attribute__((ext_vector_type(4))) unsigned uint4v;

__device__ __forceinline__ unsigned short f2bf(float f) {   // RNE
    unsigned u = __builtin_bit_cast(unsigned, f);
    u = u + 0x7fffu + ((u >> 16) & 1u);
    return (unsigned short)(u >> 16);
}
__device__ __forceinline__ unsigned packRNE(float hi, float lo) {
    return (unsigned)f2bf(lo) | ((unsigned)f2bf(hi) << 16);
}
__device__ __forceinline__ unsigned pack_trunc(float hi, float lo) {  // 1 v_perm
    return __builtin_amdgcn_perm(__builtin_bit_cast(unsigned, hi),
                                 __builtin_bit_cast(unsigned, lo), 0x07060302u);
}
__device__ __forceinline__ float rfl(float x) {
    return __builtin_bit_cast(float, __builtin_amdgcn_readfirstlane(__builtin_bit_cast(int, x)));
}
__device__ __forceinline__ f32x4 mfma16(short8 a, short8 b, f32x4 c) {
    return __builtin_amdgcn_mfma_f32_16x16x32_bf16(a, b, c, 0, 0, 0);
}
__device__ __forceinline__ unsigned bperm(int addr, unsigned v) {
    return (unsigned)__builtin_amdgcn_ds_bpermute(addr, (int)v);
}
__device__ __forceinline__ float swz1f(float v){ return __builtin_bit_cast(float, __builtin_amdgcn_ds_swizzle(__builtin_bit_cast(int, v), 0x041F)); }
__device__ __forceinline__ float swz2f(float v){ return __builtin_bit_cast(float, __builtin_amdgcn_ds_swizzle(__builtin_bit_cast(int, v), 0x081F)); }
__device__ __forceinline__ unsigned swz1u(unsigned v){ return (unsigned)__builtin_amdgcn_ds_swizzle((int)v, 0x041F); }
__device__ __forceinline__ float sigf(float x) { return __builtin_amdgcn_rcpf(1.f + __expf(-x)); }
__device__ __forceinline__ float tanhfast(float x) {
    float e = __expf(2.f * x);
    return 1.f - 2.f * __builtin_amdgcn_rcpf(e + 1.f);
}
__device__ __forceinline__ f32x4 ld4(const float* p) { return *(const f32x4*)p; }

// relu + trunc-pack 8 ch -> 4 u32, oob-zero
__device__ __forceinline__ void packC(unsigned* P, f32x4 a0, f32x4 a1, bool oob) {
    float r0 = fmaxf(a0[0], 0.f), r1 = fmaxf(a0[1], 0.f), r2 = fmaxf(a0[2], 0.f), r3 = fmaxf(a0[3], 0.f);
    float s0 = fmaxf(a1[0], 0.f), s1 = fmaxf(a1[1], 0.f), s2 = fmaxf(a1[2], 0.f), s3 = fmaxf(a1[3], 0.f);
    P[0] = pack_trunc(r1, r0); P[1] = pack_trunc(r3, r2);
    P[2] = pack_trunc(s1, s0); P[3] = pack_trunc(s3, s2);
    if (oob) { P[0] = 0u; P[1] = 0u; P[2] = 0u; P[3] = 0u; }
}

__global__ __launch_bounds__(256, 1) void r2p2_fused(
    const float* __restrict__ z, const float* __restrict__ past, const float* __restrict__ lidar,
    const float* __restrict__ w0, const float* __restrict__ b0,
    const float* __restrict__ w1, const float* __restrict__ b1,
    const float* __restrict__ w2, const float* __restrict__ b2,
    const float* __restrict__ w3, const float* __restrict__ b3,
    const float* __restrict__ enc_wih, const float* __restrict__ enc_whh,
    const float* __restrict__ enc_bih, const float* __restrict__ enc_bhh,
    const float* __restrict__ dec_wih, const float* __restrict__ dec_whh,
    const float* __restrict__ dec_bih, const float* __restrict__ dec_bhh,
    const float* __restrict__ mw1, const float* __restrict__ mb1,
    const float* __restrict__ mw2, const float* __restrict__ mb2,
    float* __restrict__ out) {

    const int tid = threadIdx.x, b = blockIdx.x;
    const int wid = tid >> 6, lane = tid & 63;
    const int n = lane & 15, q = lane >> 4, e = n & 1;
    const int pc0 = ((n >> 2) << 3) | (n & 3);   // permuted channel for A-row n, tile 0

    __shared__ __align__(16) unsigned sLID[104 * 104];   // bf16x2 lidar, zero border
    __shared__ __align__(16) float HVf[32];              // enc h f32 (natural order)
    __shared__ __align__(16) short HV2[32];              // enc h bf16
    __shared__ __align__(16) float PASTs[40];
    __shared__ __align__(16) float ZVs[64];
    __shared__ __align__(16) float MMs[132];             // composed MLP M[4][32] + c[4]

    // ---- wave0 persistent state ----
    short8 A0[2], A1f[2][4], A2f[2][4], A3f[2][4];
    short8 AdiR[2], AdiZ[2], AdiN[2], AdhR[2], AdhZ[2], AdhN[2];
    f32x4 cb0[2], cb1[2], cb2[2], cb3[2];
    f32x4 gbR[2], gbZ[2], gbNi[2], gbNh[2];
    float2 wxr[4], wxz[4], wxn[4];

    if (wid == 0) {
        // ====== wave 0 prologue: prepack conv + decoder-GRU A-frags (perm rows) ======
#pragma unroll
        for (int mt = 0; mt < 2; ++mt) {
            int co = pc0 + mt * 4;
            short8 f = (short8)0;
            if (q == 0) {
#pragma unroll
                for (int j = 0; j < 8; ++j) f[j] = (short)f2bf(w0[j * 32 + co]);
            }
            A0[mt] = f;
            cb0[mt] = ld4(b0 + q * 8 + mt * 4);
            cb1[mt] = ld4(b1 + q * 8 + mt * 4);
            cb2[mt] = ld4(b2 + q * 8 + mt * 4);
            cb3[mt] = ld4(b3 + q * 8 + mt * 4);
#pragma unroll
            for (int ks = 0; ks < 4; ++ks) {
                short8 f1, f2v, f3;
#pragma unroll
                for (int j = 0; j < 8; ++j) {
                    int kk = (ks * 32 + q * 8 + j) * 32 + co;
                    f1[j]  = (short)f2bf(w1[kk]);
                    f2v[j] = (short)f2bf(w2[kk]);
                    f3[j]  = (short)f2bf(w3[kk]);
                }
                A1f[mt][ks] = f1; A2f[mt][ks] = f2v; A3f[mt][ks] = f3;
            }
            short8 fiR, fiZ, fiN, fhR, fhZ, fhN;
#pragma unroll
            for (int j = 0; j < 8; ++j) {
                fiR[j] = (short)f2bf(dec_wih[(co)*34 + 2 + q * 8 + j]);
                fiZ[j] = (short)f2bf(dec_wih[(32 + co) * 34 + 2 + q * 8 + j]);
                fiN[j] = (short)f2bf(dec_wih[(64 + co) * 34 + 2 + q * 8 + j]);
                fhR[j] = (short)f2bf(dec_whh[(co)*32 + q * 8 + j]);
                fhZ[j] = (short)f2bf(dec_whh[(32 + co) * 32 + q * 8 + j]);
                fhN[j] = (short)f2bf(dec_whh[(64 + co) * 32 + q * 8 + j]);
            }
            AdiR[mt] = fiR; AdiZ[mt] = fiZ; AdiN[mt] = fiN;
            AdhR[mt] = fhR; AdhZ[mt] = fhZ; AdhN[mt] = fhN;
            gbR[mt]  = ld4(dec_bih + q * 8 + mt * 4)      + ld4(dec_bhh + q * 8 + mt * 4);
            gbZ[mt]  = ld4(dec_bih + 32 + q * 8 + mt * 4) + ld4(dec_bhh + 32 + q * 8 + mt * 4);
            gbNi[mt] = ld4(dec_bih + 64 + q * 8 + mt * 4);
            gbNh[mt] = ld4(dec_bhh + 64 + q * 8 + mt * 4);
        }
#pragma unroll
        for (int r = 0; r < 4; ++r) {
            int c = q * 8 + e * 4 + r;
            wxr[r] = *(const float2*)(dec_wih + c * 34);
            wxz[r] = *(const float2*)(dec_wih + (32 + c) * 34);
            wxn[r] = *(const float2*)(dec_wih + (64 + c) * 34);
        }
    } else if (wid == 1) {
        // ====== wave 1: register-GRU encoder ======
        short8 AehR[2], AehZ[2], AehN[2];
        f32x4 egR[2], egZ[2], egNh[2];
#pragma unroll
        for (int mt = 0; mt < 2; ++mt) {
            int co = pc0 + mt * 4;
            short8 fR, fZ, fN;
#pragma unroll
            for (int j = 0; j < 8; ++j) {
                fR[j] = (short)f2bf(enc_whh[(co)*32 + q * 8 + j]);
                fZ[j] = (short)f2bf(enc_whh[(32 + co) * 32 + q * 8 + j]);
                fN[j] = (short)f2bf(enc_whh[(64 + co) * 32 + q * 8 + j]);
            }
            AehR[mt] = fR; AehZ[mt] = fZ; AehN[mt] = fN;
            egR[mt]  = ld4(enc_bih + q * 8 + mt * 4)      + ld4(enc_bhh + q * 8 + mt * 4);
            egZ[mt]  = ld4(enc_bih + 32 + q * 8 + mt * 4) + ld4(enc_bhh + 32 + q * 8 + mt * 4);
            egNh[mt] = ld4(enc_bhh + 64 + q * 8 + mt * 4);
        }
        f32x4 ebni = ld4(enc_bih + 64 + q * 8 + e * 4);
        float2 wexr[4], wexz[4], wexn[4];
#pragma unroll
        for (int r = 0; r < 4; ++r) {
            int c = q * 8 + e * 4 + r;
            wexr[r] = *(const float2*)(enc_wih + c * 2);
            wexz[r] = *(const float2*)(enc_wih + (32 + c) * 2);
            wexn[r] = *(const float2*)(enc_wih + (64 + c) * 2);
        }
        if (lane < 20) *(float2*)&PASTs[2 * lane] = *(const float2*)(past + b * 40 + 2 * lane);
        float hq[4] = {0.f, 0.f, 0.f, 0.f};
        short8 hfr = (short8)0;
        asm volatile("s_waitcnt lgkmcnt(0)" ::: "memory");
#pragma unroll 1
        for (int t = 0; t < 20; ++t) {
            float2 xp = *(const float2*)&PASTs[2 * t];
            f32x4 gr0 = mfma16(AehR[0], hfr, egR[0]),  gr1 = mfma16(AehR[1], hfr, egR[1]);
            f32x4 gz0 = mfma16(AehZ[0], hfr, egZ[0]),  gz1 = mfma16(AehZ[1], hfr, egZ[1]);
            f32x4 gh0 = mfma16(AehN[0], hfr, egNh[0]), gh1 = mfma16(AehN[1], hfr, egNh[1]);
            f32x4 grS = e ? gr1 : gr0, gzS = e ? gz1 : gz0, ghS = e ? gh1 : gh0;
            float hn[4];
#pragma unroll
            for (int r = 0; r < 4; ++r) {
                float rp = grS[r] + xp.x * wexr[r].x + xp.y * wexr[r].y;
                float zp = gzS[r] + xp.x * wexz[r].x + xp.y * wexz[r].y;
                float pi = ebni[r] + xp.x * wexn[r].x + xp.y * wexn[r].y;
                float rr = sigf(rp), zz = sigf(zp);
                float tn = tanhfast(fmaf(rr, ghS[r], pi));
                float hv = tn + zz * (hq[r] - tn);
                hq[r] = hv; hn[r] = hv;
            }
            unsigned hu0 = packRNE(hn[1], hn[0]), hu1 = packRNE(hn[3], hn[2]);
            unsigned po0 = swz1u(hu0), po1 = swz1u(hu1);
            uint4v hv4;
            hv4[0] = e ? po0 : hu0; hv4[1] = e ? po1 : hu1;
            hv4[2] = e ? hu0 : po0; hv4[3] = e ? hu1 : po1;
            hfr = __builtin_bit_cast(short8, hv4);
        }
        if (n < 2) {   // e == n: write natural-order handoff
            f32x4 hv = {hq[0], hq[1], hq[2], hq[3]};
            *(f32x4*)&HVf[q * 8 + n * 4] = hv;
            uint2 hw; hw.x = packRNE(hq[1], hq[0]); hw.y = packRNE(hq[3], hq[2]);
            *(uint2*)&HV2[q * 8 + n * 4] = hw;
        }
    } else {
        // ====== waves 2-3: z, composed MLP, lidar staging ======
        int st = tid - 128;   // 0..127
        if (st < 60) ZVs[st] = z[b * 60 + st];
        {
            int j = st >> 5, k = st & 31;
            float acc = 0.f;
#pragma unroll 4
            for (int m = 0; m < 512; ++m) acc = fmaf(mw2[j * 512 + m], mw1[m * 32 + k], acc);
            MMs[j * 32 + k] = acc;
            if (st < 4) {
                float c = mb2[st];
#pragma unroll 4
                for (int m = 0; m < 512; ++m) c = fmaf(mw2[st * 512 + m], mb1[m], c);
                MMs[128 + st] = c;
            }
        }
        for (int i = st; i < 816; i += 128) {   // zero border
            int idx = (i < 416) ? (10400 + i) : ((((i - 416) >> 2) * 104) + 100 + ((i - 416) & 3));
            sLID[idx] = 0u;
        }
        const float4* lp4 = (const float4*)(lidar + (size_t)b * 20000);
#pragma unroll 4
        for (int i = st; i < 5000; i += 128) {   // interior: 2 px per float4
            int r = (int)(((unsigned)i * 5243u) >> 18);   // i / 50
            int c2 = i - r * 50;
            float4 v = lp4[i];
            int o = r * 104 + 2 * c2;
            sLID[o]     = pack_trunc(v.y, v.x);
            sLID[o + 1] = pack_trunc(v.w, v.z);
        }
    }

    __syncthreads();
    if (wid != 0) return;

    // ====== wave 0: autoregressive decode — zero LDS writes, zero barriers ======
    short8 Am = (short8)0;
    if (n < 4) {
#pragma unroll
        for (int j = 0; j < 8; ++j) Am[j] = (short)f2bf(MMs[n * 32 + q * 8 + j]);
    }
    f32x4 mcv = {0.f, 0.f, 0.f, 0.f};
    if (q == 0) mcv = *(const f32x4*)(MMs + 128);
    float hq[4];
    { f32x4 hv = *(const f32x4*)&HVf[q * 8 + e * 4]; hq[0] = hv[0]; hq[1] = hv[1]; hq[2] = hv[2]; hq[3] = hv[3]; }
    short8 hfr = *(const short8*)&HV2[q * 8];

    float q0 = past[b * 40 + 38], q1 = past[b * 40 + 39];
    float p0 = past[b * 40 + 36], p1 = past[b * 40 + 37];
    float la = 0.f;

    // hoisted geometry
    int py0a = n / 5, px0a = n % 5;
    int pe0b = (16 + n < 25) ? 16 + n : 24;
    int py0b = pe0b / 5, px0b = pe0b - py0b * 5;
    int ofs0a[4], ofs0b[4];
#pragma unroll
    for (int tp = 0; tp < 4; ++tp) {
        ofs0a[tp] = (py0a + (tp >> 1)) * 104 + px0a + (tp & 1);
        ofs0b[tp] = (py0b + (tp >> 1)) * 104 + px0b + (tp & 1);
    }
    int py1 = n >> 2, px1 = n & 3;
    int adr1[4], sel1m[4];
#pragma unroll
    for (int ks = 0; ks < 4; ++ks) {
        int p = (py1 + (ks >> 1)) * 5 + px1 + (ks & 1);
        adr1[ks] = (q * 16 + (p & 15)) * 4;
        sel1m[ks] = (p >= 16);
    }
    int pe2 = (n < 9) ? n : 8, py2 = pe2 / 3, px2 = pe2 - py2 * 3;
    int adr2[4];
#pragma unroll
    for (int ks = 0; ks < 4; ++ks) adr2[ks] = (q * 16 + (py2 + (ks >> 1)) * 4 + px2 + (ks & 1)) * 4;
    int pe3 = n & 3, py3 = pe3 >> 1, px3 = pe3 & 1;
    int adr3[4];
#pragma unroll
    for (int ks = 0; ks < 4; ++ks) adr3[ks] = (q * 16 + (py3 + (ks >> 1)) * 3 + px3 + (ks & 1)) * 4;
    const f32x4 zf4 = {0.f, 0.f, 0.f, 0.f};

#pragma unroll 1
    for (int t = 0; t < 30; ++t) {
        float f0 = fminf(fmaxf(floorf(q0), 0.f), 98.f);
        float f1v = fminf(fmaxf(floorf(q1), 0.f), 98.f);
        int fy = (int)f0, fx = (int)f1v;
        float ay = fminf(fmaxf(q0 - f0, 0.f), 1.f);
        float ax = fminf(fmaxf(q1 - f1v, 0.f), 1.f);
        int base = fy * 104 + fx;
        int limy = 100 - fy, limx = 100 - fx;

        // ---- conv0 ----
        short8 bfa = (short8)0, bfb = (short8)0;
        if (q == 0) {
            uint4v ua, ub;
#pragma unroll
            for (int tp = 0; tp < 4; ++tp) { ua[tp] = sLID[base + ofs0a[tp]]; ub[tp] = sLID[base + ofs0b[tp]]; }
            bfa = __builtin_bit_cast(short8, ua);
            bfb = __builtin_bit_cast(short8, ub);
        }
        f32x4 ca0 = mfma16(A0[0], bfa, cb0[0]);
        f32x4 ca1 = mfma16(A0[1], bfa, cb0[1]);
        f32x4 cB0 = mfma16(A0[0], bfb, cb0[0]);
        f32x4 cB1 = mfma16(A0[1], bfb, cb0[1]);
        unsigned Pa[4], Pb[4];
        packC(Pa, ca0, ca1, (py0a >= limy) || (px0a >= limx));
        packC(Pb, cB0, cB1, (py0b >= limy) || (px0b >= limx));

        // ---- conv1: B via two-set bpermute ----
        short8 bf1[4];
#pragma unroll
        for (int ks = 0; ks < 4; ++ks) {
            uint4v bu;
#pragma unroll
            for (int u = 0; u < 4; ++u) {
                unsigned va = bperm(adr1[ks], Pa[u]);
                unsigned vb = bperm(adr1[ks], Pb[u]);
                bu[u] = sel1m[ks] ? vb : va;
            }
            bf1[ks] = __builtin_bit_cast(short8, bu);
        }
        {
            f32x4 aA = mfma16(A1f[0][0], bf1[0], cb1[0]); aA = mfma16(A1f[0][1], bf1[1], aA);
            f32x4 aB = mfma16(A1f[0][2], bf1[2], zf4);    aB = mfma16(A1f[0][3], bf1[3], aB);
            f32x4 bA = mfma16(A1f[1][0], bf1[0], cb1[1]); bA = mfma16(A1f[1][1], bf1[1], bA);
            f32x4 bB = mfma16(A1f[1][2], bf1[2], zf4);    bB = mfma16(A1f[1][3], bf1[3], bB);
            f32x4 o0 = aA + aB, o1 = bA + bB;
            packC(Pa, o0, o1, (py1 >= limy) || (px1 >= limx));   // reuse Pa as conv1 out
        }

        // ---- conv2 ----
        short8 bf2v[4];
#pragma unroll
        for (int ks = 0; ks < 4; ++ks) {
            uint4v bu;
#pragma unroll
            for (int u = 0; u < 4; ++u) bu[u] = bperm(adr2[ks], Pa[u]);
            bf2v[ks] = __builtin_bit_cast(short8, bu);
        }
        {
            f32x4 aA = mfma16(A2f[0][0], bf2v[0], cb2[0]); aA = mfma16(A2f[0][1], bf2v[1], aA);
            f32x4 aB = mfma16(A2f[0][2], bf2v[2], zf4);    aB = mfma16(A2f[0][3], bf2v[3], aB);
            f32x4 bA = mfma16(A2f[1][0], bf2v[0], cb2[1]); bA = mfma16(A2f[1][1], bf2v[1], bA);
            f32x4 bB = mfma16(A2f[1][2], bf2v[2], zf4);    bB = mfma16(A2f[1][3], bf2v[3], bB);
            f32x4 o0 = aA + aB, o1 = bA + bB;
            packC(Pb, o0, o1, (py2 >= limy) || (px2 >= limx));   // Pb = conv2 out
        }

        // ---- conv3 + bilinear butterfly (in-register) ----
        short8 bf3v[4];
#pragma unroll
        for (int ks = 0; ks < 4; ++ks) {
            uint4v bu;
#pragma unroll
            for (int u = 0; u < 4; ++u) bu[u] = bperm(adr3[ks], Pb[u]);
            bf3v[ks] = __builtin_bit_cast(short8, bu);
        }
        short8 xf;
        {
            f32x4 aA = mfma16(A3f[0][0], bf3v[0], cb3[0]); aA = mfma16(A3f[0][1], bf3v[1], aA);
            f32x4 aB = mfma16(A3f[0][2], bf3v[2], zf4);    aB = mfma16(A3f[0][3], bf3v[3], aB);
            f32x4 bA = mfma16(A3f[1][0], bf3v[0], cb3[1]); bA = mfma16(A3f[1][1], bf3v[1], bA);
            f32x4 bB = mfma16(A3f[1][2], bf3v[2], zf4);    bB = mfma16(A3f[1][3], bf3v[3], bB);
            f32x4 o0 = aA + aB, o1 = bA + bB;
            float wy = (n & 2) ? ay : 1.f - ay;
            float wx = (n & 1) ? ax : 1.f - ax;
            float w = wy * wx;
            float t0[4], t1[4];
#pragma unroll
            for (int r = 0; r < 4; ++r) { t0[r] = fmaxf(o0[r], 0.f) * w; t1[r] = fmaxf(o1[r], 0.f) * w; }
#pragma unroll
            for (int r = 0; r < 4; ++r) { t0[r] += swz1f(t0[r]); t1[r] += swz1f(t1[r]); }
#pragma unroll
            for (int r = 0; r < 4; ++r) { t0[r] += swz2f(t0[r]); t1[r] += swz2f(t1[r]); }
            uint4v xu;
            xu[0] = packRNE(t0[1], t0[0]); xu[1] = packRNE(t0[3], t0[2]);
            xu[2] = packRNE(t1[1], t1[0]); xu[3] = packRNE(t1[3], t1[2]);
            xf = __builtin_bit_cast(short8, xu);
        }

        // ---- decoder GRU: 12 MFMAs depth<=2, activation in-register ----
        f32x4 gr0 = mfma16(AdiR[0], xf, gbR[0]); gr0 = mfma16(AdhR[0], hfr, gr0);
        f32x4 gr1 = mfma16(AdiR[1], xf, gbR[1]); gr1 = mfma16(AdhR[1], hfr, gr1);
        f32x4 gz0 = mfma16(AdiZ[0], xf, gbZ[0]); gz0 = mfma16(AdhZ[0], hfr, gz0);
        f32x4 gz1 = mfma16(AdiZ[1], xf, gbZ[1]); gz1 = mfma16(AdhZ[1], hfr, gz1);
        f32x4 gi0 = mfma16(AdiN[0], xf, gbNi[0]);
        f32x4 gi1 = mfma16(AdiN[1], xf, gbNi[1]);
        f32x4 gh0 = mfma16(AdhN[0], hfr, gbNh[0]);
        f32x4 gh1 = mfma16(AdhN[1], hfr, gbNh[1]);
        f32x4 grS = e ? gr1 : gr0, gzS = e ? gz1 : gz0, giS = e ? gi1 : gi0, ghS = e ? gh1 : gh0;
        float hn[4];
#pragma unroll
        for (int r = 0; r < 4; ++r) {
            float rp = grS[r] + q0 * wxr[r].x + q1 * wxr[r].y;
            float zp = gzS[r] + q0 * wxz[r].x + q1 * wxz[r].y;
            float pi = giS[r] + q0 * wxn[r].x + q1 * wxn[r].y;
            float rr = sigf(rp), zz = sigf(zp);
            float tn = tanhfast(fmaf(rr, ghS[r], pi));
            float hv = tn + zz * (hq[r] - tn);
            hq[r] = hv; hn[r] = hv;
        }
        unsigned hu0 = packRNE(hn[1], hn[0]), hu1 = packRNE(hn[3], hn[2]);
        unsigned po0 = swz1u(hu0), po1 = swz1u(hu1);
        uint4v hv4;
        hv4[0] = e ? po0 : hu0; hv4[1] = e ? po1 : hu1;
        hv4[2] = e ? hu0 : po0; hv4[3] = e ? hu1 : po1;
        hfr = __builtin_bit_cast(short8, hv4);

        // ---- composed MLP head + tail ----
        f32x4 ls = mfma16(Am, hfr, mcv);
        float l2 = ls[2], l3 = ls[3];
        float s0 = fmaxf(l2, 0.f) + __logf(1.f + __expf(-fabsf(l2)));
        float s1 = fmaxf(l3, 0.f) + __logf(1.f + __expf(-fabsf(l3)));
        float2 zv = *(const float2*)&ZVs[2 * t];
        float ny0 = 2.f * q0 - p0 + ls[0] + s0 * zv.x;
        float ny1 = 2.f * q1 - p1 + ls[1] + s1 * zv.y;
        if (lane == 0) {
            float2 o2 = {ny0, ny1};
            *(float2*)(out + b * 60 + 2 * t) = o2;
        }
        la += __logf(s0 * s1);
        p0 = q0; p1 = q1;
        q0 = rfl(ny0); q1 = rfl(ny1);
    }
    if (lane == 0) out[15360 + b] = la;
}

extern "C" void kernel_launch(void* const* d_in, const int* in_sizes, int n_in,
                              void* d_out, int out_size, void* d_ws, size_t ws_size,
                              hipStream_t stream) {
    const float* z    = (const float*)d_in[0];
    const float* past = (const float*)d_in[1];
    const float* lid  = (const float*)d_in[2];
    const float* c0w = (const float*)d_in[3];  const float* c0b = (const float*)d_in[4];
    const float* c1w = (const float*)d_in[5];  const float* c1b = (const float*)d_in[6];
    const float* c2w = (const float*)d_in[7];  const float* c2b = (const float*)d_in[8];
    const float* c3w = (const float*)d_in[9];  const float* c3b = (const float*)d_in[10];
    const float* ewih = (const float*)d_in[11]; const float* ewhh = (const float*)d_in[12];
    const float* ebih = (const float*)d_in[13]; const float* ebhh = (const float*)d_in[14];
    const float* dwih = (const float*)d_in[15]; const float* dwhh = (const float*)d_in[16];
    const float* dbih = (const float*)d_in[17]; const float* dbhh = (const float*)d_in[18];
    const float* mw1 = (const float*)d_in[19]; const float* mb1 = (const float*)d_in[20];
    const float* mw2 = (const float*)d_in[21]; const float* mb2 = (const float*)d_in[22];
    float* out = (float*)d_out;

    r2p2_fused<<<256, 256, 0, stream>>>(z, past, lid, c0w, c0b, c1w, c1b, c2w, c2b, c3w, c3b,
                                        ewih, ewhh, ebih, ebhh, dwih, dwhh, dbih, dbhh,
                                        mw1, mb1, mw2, mb2, out);
}

// Round 5
// 188.758 us; speedup vs baseline: 1.7473x; 1.1456x over previous
//
#include <hip/hip_runtime.h>
#include <math.h>

typedef __attribute__((ext_vector_type(8))) short    short8;
typedef __attribute__((ext_vector_type(4))) float    f32x4;
typedef __attribute__((ext_vector_type(4))) unsigned uint4v;

#define FRAG0 256   // u32 offset of frag region in ws

__device__ __forceinline__ unsigned short f2bf(float f) {   // RNE
    unsigned u = __builtin_bit_cast(unsigned, f);
    u = u + 0x7fffu + ((u >> 16) & 1u);
    return (unsigned short)(u >> 16);
}
__device__ __forceinline__ unsigned packRNE(float hi, float lo) {
    return (unsigned)f2bf(lo) | ((unsigned)f2bf(hi) << 16);
}
__device__ __forceinline__ unsigned pack_trunc(float hi, float lo) {  // 1 v_perm
    return __builtin_amdgcn_perm(__builtin_bit_cast(unsigned, hi),
                                 __builtin_bit_cast(unsigned, lo), 0x07060302u);
}
__device__ __forceinline__ float rfl(float x) {
    return __builtin_bit_cast(float, __builtin_amdgcn_readfirstlane(__builtin_bit_cast(int, x)));
}
__device__ __forceinline__ f32x4 mfma16(short8 a, short8 b, f32x4 c) {
    return __builtin_amdgcn_mfma_f32_16x16x32_bf16(a, b, c, 0, 0, 0);
}
__device__ __forceinline__ unsigned bperm(int addr, unsigned v) {
    return (unsigned)__builtin_amdgcn_ds_bpermute(addr, (int)v);
}
__device__ __forceinline__ float swz1f(float v){ return __builtin_bit_cast(float, __builtin_amdgcn_ds_swizzle(__builtin_bit_cast(int, v), 0x041F)); }
__device__ __forceinline__ float swz2f(float v){ return __builtin_bit_cast(float, __builtin_amdgcn_ds_swizzle(__builtin_bit_cast(int, v), 0x081F)); }
__device__ __forceinline__ unsigned swz1u(unsigned v){ return (unsigned)__builtin_amdgcn_ds_swizzle((int)v, 0x041F); }
__device__ __forceinline__ float sigf(float x) { return __builtin_amdgcn_rcpf(1.f + __expf(-x)); }
__device__ __forceinline__ float tanhfast(float x) {
    float e = __expf(2.f * x);
    return 1.f - 2.f * __builtin_amdgcn_rcpf(e + 1.f);
}
__device__ __forceinline__ f32x4 ld4(const float* p) { return *(const f32x4*)p; }

__device__ __forceinline__ void packC(unsigned* P, f32x4 a0, f32x4 a1, bool oob) {
    float r0 = fmaxf(a0[0], 0.f), r1 = fmaxf(a0[1], 0.f), r2 = fmaxf(a0[2], 0.f), r3 = fmaxf(a0[3], 0.f);
    float s0 = fmaxf(a1[0], 0.f), s1 = fmaxf(a1[1], 0.f), s2 = fmaxf(a1[2], 0.f), s3 = fmaxf(a1[3], 0.f);
    P[0] = pack_trunc(r1, r0); P[1] = pack_trunc(r3, r2);
    P[2] = pack_trunc(s1, s0); P[3] = pack_trunc(s3, s2);
    if (oob) { P[0] = 0u; P[1] = 0u; P[2] = 0u; P[3] = 0u; }
}

// ===================== prep kernel: MLP compose + frag prepack =====================
__global__ __launch_bounds__(256) void r2p2_prep(
    const float* __restrict__ w0, const float* __restrict__ w1,
    const float* __restrict__ w2, const float* __restrict__ w3,
    const float* __restrict__ enc_whh,
    const float* __restrict__ dec_wih, const float* __restrict__ dec_whh,
    const float* __restrict__ mw1, const float* __restrict__ mb1,
    const float* __restrict__ mw2, const float* __restrict__ mb2,
    float* __restrict__ wsf, unsigned* __restrict__ wsu) {
    const int tid = threadIdx.x, bx = blockIdx.x;
    if (bx == 0) {
        // ---- composed MLP: M[4][32] + c[4], 2 threads per output ----
        int o = tid >> 1, half = tid & 1;
        int j = o >> 5, k = o & 31;
        float acc = 0.f;
        const float* w2r = mw2 + j * 512 + half * 256;
        const float* w1c = mw1 + half * 256 * 32 + k;
#pragma unroll 8
        for (int m = 0; m < 256; ++m) acc = fmaf(w2r[m], w1c[m * 32], acc);
        float part = __shfl_xor(acc, 1, 64);
        if (half == 0) wsf[o] = acc + part;
        if (tid < 8) {
            int oc = tid >> 1, hc = tid & 1;
            float a2 = 0.f;
            const float* w2c = mw2 + oc * 512 + hc * 256;
            const float* b1c = mb1 + hc * 256;
#pragma unroll 8
            for (int m = 0; m < 256; ++m) a2 = fmaf(w2c[m], b1c[m], a2);
            float p2 = __shfl_xor(a2, 1, 64);
            if (hc == 0) wsf[128 + oc] = a2 + p2 + mb2[oc];
        }
        return;
    }
    // ---- frag prepack: 44 frags x 64 lanes, cells split over blocks 1..7 ----
    int base = (bx - 1) * 416;
    for (int c = base + tid; c < base + 416 && c < 2816; c += 256) {
        int f = c >> 6, lane = c & 63;
        int n = lane & 15, q = lane >> 4;
        int pc0 = ((n >> 2) << 3) | (n & 3);
        float v[8];
        if (f < 2) {
            int co = pc0 + f * 4;
#pragma unroll
            for (int j = 0; j < 8; ++j) v[j] = (q == 0) ? w0[j * 32 + co] : 0.f;
        } else if (f < 26) {
            int t = f - 2;
            const float* W = (t < 8) ? w1 : (t < 16) ? w2 : w3;
            t &= 7;
            int mt = t >> 2, ks = t & 3, co = pc0 + mt * 4;
#pragma unroll
            for (int j = 0; j < 8; ++j) v[j] = W[(ks * 32 + q * 8 + j) * 32 + co];
        } else if (f < 32) {
            int t = f - 26, gate = t >> 1, mt = t & 1;
            int row = gate * 32 + pc0 + mt * 4;
#pragma unroll
            for (int j = 0; j < 8; ++j) v[j] = dec_wih[row * 34 + 2 + q * 8 + j];
        } else if (f < 38) {
            int t = f - 32, gate = t >> 1, mt = t & 1;
            int row = gate * 32 + pc0 + mt * 4;
#pragma unroll
            for (int j = 0; j < 8; ++j) v[j] = dec_whh[row * 32 + q * 8 + j];
        } else {
            int t = f - 38, gate = t >> 1, mt = t & 1;
            int row = gate * 32 + pc0 + mt * 4;
#pragma unroll
            for (int j = 0; j < 8; ++j) v[j] = enc_whh[row * 32 + q * 8 + j];
        }
        uint4v u;
        u[0] = packRNE(v[1], v[0]); u[1] = packRNE(v[3], v[2]);
        u[2] = packRNE(v[5], v[4]); u[3] = packRNE(v[7], v[6]);
        *(uint4v*)(wsu + FRAG0 + f * 256 + lane * 4) = u;
    }
}

// ===================== main kernel =====================
__global__ __launch_bounds__(256, 1) void r2p2_main(
    const float* __restrict__ z, const float* __restrict__ past, const float* __restrict__ lidar,
    const float* __restrict__ b0, const float* __restrict__ b1,
    const float* __restrict__ b2, const float* __restrict__ b3,
    const float* __restrict__ enc_wih, const float* __restrict__ enc_bih, const float* __restrict__ enc_bhh,
    const float* __restrict__ dec_wih, const float* __restrict__ dec_bih, const float* __restrict__ dec_bhh,
    const float* __restrict__ wsf, const unsigned* __restrict__ wsu,
    float* __restrict__ out) {

    const int tid = threadIdx.x, b = blockIdx.x;
    const int wid = tid >> 6, lane = tid & 63;
    const int n = lane & 15, q = lane >> 4, e = n & 1;

    __shared__ __align__(16) unsigned sLID[104 * 104];
    __shared__ __align__(16) float PASTs[40];
    __shared__ __align__(16) float ZVs[64];

    if (wid != 0) {
        // ====== waves 1-3: lidar staging + z ======
        int st = tid - 64;   // 0..191
        if (st < 60) ZVs[st] = z[b * 60 + st];
        for (int i = st; i < 816; i += 192) {   // zero border
            int idx = (i < 416) ? (10400 + i) : ((((i - 416) >> 2) * 104) + 100 + ((i - 416) & 3));
            sLID[idx] = 0u;
        }
        const float4* lp4 = (const float4*)(lidar + (size_t)b * 20000);
#pragma unroll 4
        for (int i = st; i < 5000; i += 192) {
            int r = (int)(((unsigned)i * 5243u) >> 18);   // i / 50
            int c2 = i - r * 50;
            float4 v = lp4[i];
            int o = r * 104 + 2 * c2;
            sLID[o]     = pack_trunc(v.y, v.x);
            sLID[o + 1] = pack_trunc(v.w, v.z);
        }
        __syncthreads();
        return;
    }

    // ====== wave 0: coalesced frag loads ======
    uint4v FR[44];
#pragma unroll
    for (int f = 0; f < 44; ++f) FR[f] = *(const uint4v*)(wsu + FRAG0 + f * 256 + lane * 4);
#define FRG(f) __builtin_bit_cast(short8, FR[f])

    // biases (contiguous ld4)
    f32x4 cb0[2], cb1[2], cb2[2], cb3[2], gbR[2], gbZ[2], gbNi[2], gbNh[2];
    f32x4 egR[2], egZ[2], egNh[2];
#pragma unroll
    for (int mt = 0; mt < 2; ++mt) {
        int o = q * 8 + mt * 4;
        cb0[mt] = ld4(b0 + o); cb1[mt] = ld4(b1 + o); cb2[mt] = ld4(b2 + o); cb3[mt] = ld4(b3 + o);
        gbR[mt]  = ld4(dec_bih + o)      + ld4(dec_bhh + o);
        gbZ[mt]  = ld4(dec_bih + 32 + o) + ld4(dec_bhh + 32 + o);
        gbNi[mt] = ld4(dec_bih + 64 + o);
        gbNh[mt] = ld4(dec_bhh + 64 + o);
        egR[mt]  = ld4(enc_bih + o)      + ld4(enc_bhh + o);
        egZ[mt]  = ld4(enc_bih + 32 + o) + ld4(enc_bhh + 32 + o);
        egNh[mt] = ld4(enc_bhh + 64 + o);
    }
    f32x4 ebni = ld4(enc_bih + 64 + q * 8 + e * 4);
    float2 wxr[4], wxz[4], wxn[4], wexr[4], wexz[4], wexn[4];
#pragma unroll
    for (int r = 0; r < 4; ++r) {
        int c = q * 8 + e * 4 + r;
        wxr[r]  = *(const float2*)(dec_wih + c * 34);
        wxz[r]  = *(const float2*)(dec_wih + (32 + c) * 34);
        wxn[r]  = *(const float2*)(dec_wih + (64 + c) * 34);
        wexr[r] = *(const float2*)(enc_wih + c * 2);
        wexz[r] = *(const float2*)(enc_wih + (32 + c) * 2);
        wexn[r] = *(const float2*)(enc_wih + (64 + c) * 2);
    }
    short8 Am = (short8)0;
    if (n < 4) {
#pragma unroll
        for (int j = 0; j < 8; ++j) Am[j] = (short)f2bf(wsf[n * 32 + q * 8 + j]);
    }
    f32x4 mcv = {0.f, 0.f, 0.f, 0.f};
    if (q == 0) mcv = *(const f32x4*)(wsf + 128);

    if (lane < 20) *(float2*)&PASTs[2 * lane] = *(const float2*)(past + b * 40 + 2 * lane);
    float q0 = past[b * 40 + 38], q1 = past[b * 40 + 39];
    float p0 = past[b * 40 + 36], p1 = past[b * 40 + 37];
    asm volatile("s_waitcnt lgkmcnt(0)" ::: "memory");

    // ====== encoder: register GRU, 20 steps ======
    float hq[4] = {0.f, 0.f, 0.f, 0.f};
    short8 hfr = (short8)0;
#pragma unroll 1
    for (int t = 0; t < 20; ++t) {
        float2 xp = *(const float2*)&PASTs[2 * t];
        f32x4 gr0 = mfma16(FRG(38), hfr, egR[0]),  gr1 = mfma16(FRG(39), hfr, egR[1]);
        f32x4 gz0 = mfma16(FRG(40), hfr, egZ[0]),  gz1 = mfma16(FRG(41), hfr, egZ[1]);
        f32x4 gh0 = mfma16(FRG(42), hfr, egNh[0]), gh1 = mfma16(FRG(43), hfr, egNh[1]);
        f32x4 grS = e ? gr1 : gr0, gzS = e ? gz1 : gz0, ghS = e ? gh1 : gh0;
        float hn[4];
#pragma unroll
        for (int r = 0; r < 4; ++r) {
            float rp = grS[r] + xp.x * wexr[r].x + xp.y * wexr[r].y;
            float zp = gzS[r] + xp.x * wexz[r].x + xp.y * wexz[r].y;
            float pi = ebni[r] + xp.x * wexn[r].x + xp.y * wexn[r].y;
            float rr = sigf(rp), zz = sigf(zp);
            float tn = tanhfast(fmaf(rr, ghS[r], pi));
            float hv = tn + zz * (hq[r] - tn);
            hq[r] = hv; hn[r] = hv;
        }
        unsigned hu0 = packRNE(hn[1], hn[0]), hu1 = packRNE(hn[3], hn[2]);
        unsigned po0 = swz1u(hu0), po1 = swz1u(hu1);
        uint4v hv4;
        hv4[0] = e ? po0 : hu0; hv4[1] = e ? po1 : hu1;
        hv4[2] = e ? hu0 : po0; hv4[3] = e ? hu1 : po1;
        hfr = __builtin_bit_cast(short8, hv4);
    }

    __syncthreads();   // join staging waves

    // hoisted geometry
    const int pc0 = ((n >> 2) << 3) | (n & 3); (void)pc0;
    int py0a = n / 5, px0a = n % 5;
    int pe0b = (16 + n < 25) ? 16 + n : 24;
    int py0b = pe0b / 5, px0b = pe0b - py0b * 5;
    int ofs0a[4], ofs0b[4];
#pragma unroll
    for (int tp = 0; tp < 4; ++tp) {
        ofs0a[tp] = (py0a + (tp >> 1)) * 104 + px0a + (tp & 1);
        ofs0b[tp] = (py0b + (tp >> 1)) * 104 + px0b + (tp & 1);
    }
    int py1 = n >> 2, px1 = n & 3;
    int adr1[4], sel1m[4];
#pragma unroll
    for (int ks = 0; ks < 4; ++ks) {
        int p = (py1 + (ks >> 1)) * 5 + px1 + (ks & 1);
        adr1[ks] = (q * 16 + (p & 15)) * 4;
        sel1m[ks] = (p >= 16);
    }
    int pe2 = (n < 9) ? n : 8, py2 = pe2 / 3, px2 = pe2 - py2 * 3;
    int adr2[4];
#pragma unroll
    for (int ks = 0; ks < 4; ++ks) adr2[ks] = (q * 16 + (py2 + (ks >> 1)) * 4 + px2 + (ks & 1)) * 4;
    int pe3 = n & 3, py3 = pe3 >> 1, px3 = pe3 & 1;
    int adr3[4];
#pragma unroll
    for (int ks = 0; ks < 4; ++ks) adr3[ks] = (q * 16 + (py3 + (ks >> 1)) * 3 + px3 + (ks & 1)) * 4;
    const f32x4 zf4 = {0.f, 0.f, 0.f, 0.f};
    float la = 0.f;

#pragma unroll 1
    for (int t = 0; t < 30; ++t) {
        float f0 = fminf(fmaxf(floorf(q0), 0.f), 98.f);
        float f1v = fminf(fmaxf(floorf(q1), 0.f), 98.f);
        int fy = (int)f0, fx = (int)f1v;
        float ay = fminf(fmaxf(q0 - f0, 0.f), 1.f);
        float ax = fminf(fmaxf(q1 - f1v, 0.f), 1.f);
        int base = fy * 104 + fx;
        int limy = 100 - fy, limx = 100 - fx;

        // ---- conv0 ----
        short8 bfa = (short8)0, bfb = (short8)0;
        if (q == 0) {
            uint4v ua, ub;
#pragma unroll
            for (int tp = 0; tp < 4; ++tp) { ua[tp] = sLID[base + ofs0a[tp]]; ub[tp] = sLID[base + ofs0b[tp]]; }
            bfa = __builtin_bit_cast(short8, ua);
            bfb = __builtin_bit_cast(short8, ub);
        }
        f32x4 ca0 = mfma16(FRG(0), bfa, cb0[0]);
        f32x4 ca1 = mfma16(FRG(1), bfa, cb0[1]);
        f32x4 cB0 = mfma16(FRG(0), bfb, cb0[0]);
        f32x4 cB1 = mfma16(FRG(1), bfb, cb0[1]);
        unsigned Pa[4], Pb[4];
        packC(Pa, ca0, ca1, (py0a >= limy) || (px0a >= limx));
        packC(Pb, cB0, cB1, (py0b >= limy) || (px0b >= limx));

        // ---- conv1 ----
        short8 bf1[4];
#pragma unroll
        for (int ks = 0; ks < 4; ++ks) {
            uint4v bu;
#pragma unroll
            for (int u = 0; u < 4; ++u) {
                unsigned va = bperm(adr1[ks], Pa[u]);
                unsigned vb = bperm(adr1[ks], Pb[u]);
                bu[u] = sel1m[ks] ? vb : va;
            }
            bf1[ks] = __builtin_bit_cast(short8, bu);
        }
        {
            f32x4 aA = mfma16(FRG(2), bf1[0], cb1[0]); aA = mfma16(FRG(3), bf1[1], aA);
            f32x4 aB = mfma16(FRG(4), bf1[2], zf4);    aB = mfma16(FRG(5), bf1[3], aB);
            f32x4 bA = mfma16(FRG(6), bf1[0], cb1[1]); bA = mfma16(FRG(7), bf1[1], bA);
            f32x4 bB = mfma16(FRG(8), bf1[2], zf4);    bB = mfma16(FRG(9), bf1[3], bB);
            f32x4 o0 = aA + aB, o1 = bA + bB;
            packC(Pa, o0, o1, (py1 >= limy) || (px1 >= limx));
        }

        // ---- conv2 ----
        short8 bf2v[4];
#pragma unroll
        for (int ks = 0; ks < 4; ++ks) {
            uint4v bu;
#pragma unroll
            for (int u = 0; u < 4; ++u) bu[u] = bperm(adr2[ks], Pa[u]);
            bf2v[ks] = __builtin_bit_cast(short8, bu);
        }
        {
            f32x4 aA = mfma16(FRG(10), bf2v[0], cb2[0]); aA = mfma16(FRG(11), bf2v[1], aA);
            f32x4 aB = mfma16(FRG(12), bf2v[2], zf4);    aB = mfma16(FRG(13), bf2v[3], aB);
            f32x4 bA = mfma16(FRG(14), bf2v[0], cb2[1]); bA = mfma16(FRG(15), bf2v[1], bA);
            f32x4 bB = mfma16(FRG(16), bf2v[2], zf4);    bB = mfma16(FRG(17), bf2v[3], bB);
            f32x4 o0 = aA + aB, o1 = bA + bB;
            packC(Pb, o0, o1, (py2 >= limy) || (px2 >= limx));
        }

        // ---- conv3 + bilinear butterfly ----
        short8 bf3v[4];
#pragma unroll
        for (int ks = 0; ks < 4; ++ks) {
            uint4v bu;
#pragma unroll
            for (int u = 0; u < 4; ++u) bu[u] = bperm(adr3[ks], Pb[u]);
            bf3v[ks] = __builtin_bit_cast(short8, bu);
        }
        short8 xf;
        {
            f32x4 aA = mfma16(FRG(18), bf3v[0], cb3[0]); aA = mfma16(FRG(19), bf3v[1], aA);
            f32x4 aB = mfma16(FRG(20), bf3v[2], zf4);    aB = mfma16(FRG(21), bf3v[3], aB);
            f32x4 bA = mfma16(FRG(22), bf3v[0], cb3[1]); bA = mfma16(FRG(23), bf3v[1], bA);
            f32x4 bB = mfma16(FRG(24), bf3v[2], zf4);    bB = mfma16(FRG(25), bf3v[3], bB);
            f32x4 o0 = aA + aB, o1 = bA + bB;
            float wy = (n & 2) ? ay : 1.f - ay;
            float wx = (n & 1) ? ax : 1.f - ax;
            float w = wy * wx;
            float t0[4], t1[4];
#pragma unroll
            for (int r = 0; r < 4; ++r) { t0[r] = fmaxf(o0[r], 0.f) * w; t1[r] = fmaxf(o1[r], 0.f) * w; }
#pragma unroll
            for (int r = 0; r < 4; ++r) { t0[r] += swz1f(t0[r]); t1[r] += swz1f(t1[r]); }
#pragma unroll
            for (int r = 0; r < 4; ++r) { t0[r] += swz2f(t0[r]); t1[r] += swz2f(t1[r]); }
            uint4v xu;
            xu[0] = packRNE(t0[1], t0[0]); xu[1] = packRNE(t0[3], t0[2]);
            xu[2] = packRNE(t1[1], t1[0]); xu[3] = packRNE(t1[3], t1[2]);
            xf = __builtin_bit_cast(short8, xu);
        }

        // ---- decoder GRU ----
        f32x4 gr0 = mfma16(FRG(26), xf, gbR[0]); gr0 = mfma16(FRG(32), hfr, gr0);
        f32x4 gr1 = mfma16(FRG(27), xf, gbR[1]); gr1 = mfma16(FRG(33), hfr, gr1);
        f32x4 gz0 = mfma16(FRG(28), xf, gbZ[0]); gz0 = mfma16(FRG(34), hfr, gz0);
        f32x4 gz1 = mfma16(FRG(29), xf, gbZ[1]); gz1 = mfma16(FRG(35), hfr, gz1);
        f32x4 gi0 = mfma16(FRG(30), xf, gbNi[0]);
        f32x4 gi1 = mfma16(FRG(31), xf, gbNi[1]);
        f32x4 gh0 = mfma16(FRG(36), hfr, gbNh[0]);
        f32x4 gh1 = mfma16(FRG(37), hfr, gbNh[1]);
        f32x4 grS = e ? gr1 : gr0, gzS = e ? gz1 : gz0, giS = e ? gi1 : gi0, ghS = e ? gh1 : gh0;
        float hn[4];
#pragma unroll
        for (int r = 0; r < 4; ++r) {
            float rp = grS[r] + q0 * wxr[r].x + q1 * wxr[r].y;
            float zp = gzS[r] + q0 * wxz[r].x + q1 * wxz[r].y;
            float pi = giS[r] + q0 * wxn[r].x + q1 * wxn[r].y;
            float rr = sigf(rp), zz = sigf(zp);
            float tn = tanhfast(fmaf(rr, ghS[r], pi));
            float hv = tn + zz * (hq[r] - tn);
            hq[r] = hv; hn[r] = hv;
        }
        unsigned hu0 = packRNE(hn[1], hn[0]), hu1 = packRNE(hn[3], hn[2]);
        unsigned po0 = swz1u(hu0), po1 = swz1u(hu1);
        uint4v hv4;
        hv4[0] = e ? po0 : hu0; hv4[1] = e ? po1 : hu1;
        hv4[2] = e ? hu0 : po0; hv4[3] = e ? hu1 : po1;
        hfr = __builtin_bit_cast(short8, hv4);

        // ---- head + tail ----
        f32x4 ls = mfma16(Am, hfr, mcv);
        float l2 = ls[2], l3 = ls[3];
        float s0 = fmaxf(l2, 0.f) + __logf(1.f + __expf(-fabsf(l2)));
        float s1 = fmaxf(l3, 0.f) + __logf(1.f + __expf(-fabsf(l3)));
        float2 zv = *(const float2*)&ZVs[2 * t];
        float ny0 = 2.f * q0 - p0 + ls[0] + s0 * zv.x;
        float ny1 = 2.f * q1 - p1 + ls[1] + s1 * zv.y;
        if (lane == 0) {
            float2 o2 = {ny0, ny1};
            *(float2*)(out + b * 60 + 2 * t) = o2;
        }
        la += __logf(s0 * s1);
        p0 = q0; p1 = q1;
        q0 = rfl(ny0); q1 = rfl(ny1);
    }
    if (lane == 0) out[15360 + b] = la;
#undef FRG
}

extern "C" void kernel_launch(void* const* d_in, const int* in_sizes, int n_in,
                              void* d_out, int out_size, void* d_ws, size_t ws_size,
                              hipStream_t stream) {
    const float* z    = (const float*)d_in[0];
    const float* past = (const float*)d_in[1];
    const float* lid  = (const float*)d_in[2];
    const float* c0w = (const float*)d_in[3];  const float* c0b = (const float*)d_in[4];
    const float* c1w = (const float*)d_in[5];  const float* c1b = (const float*)d_in[6];
    const float* c2w = (const float*)d_in[7];  const float* c2b = (const float*)d_in[8];
    const float* c3w = (const float*)d_in[9];  const float* c3b = (const float*)d_in[10];
    const float* ewih = (const float*)d_in[11]; const float* ewhh = (const float*)d_in[12];
    const float* ebih = (const float*)d_in[13]; const float* ebhh = (const float*)d_in[14];
    const float* dwih = (const float*)d_in[15]; const float* dwhh = (const float*)d_in[16];
    const float* dbih = (const float*)d_in[17]; const float* dbhh = (const float*)d_in[18];
    const float* mw1 = (const float*)d_in[19]; const float* mb1 = (const float*)d_in[20];
    const float* mw2 = (const float*)d_in[21]; const float* mb2 = (const float*)d_in[22];
    float* out = (float*)d_out;
    float* wsf = (float*)d_ws;
    unsigned* wsu = (unsigned*)d_ws;

    r2p2_prep<<<8, 256, 0, stream>>>(c0w, c1w, c2w, c3w, ewhh, dwih, dwhh,
                                     mw1, mb1, mw2, mb2, wsf, wsu);
    r2p2_main<<<256, 256, 0, stream>>>(z, past, lid, c0b, c1b, c2b, c3b,
                                       ewih, ebih, ebhh, dwih, dbih, dbhh,
                                       wsf, wsu, out);
}

// Round 6
// 184.622 us; speedup vs baseline: 1.7865x; 1.0224x over previous
//
#include <hip/hip_runtime.h>
#include <math.h>

typedef __attribute__((ext_vector_type(8))) short    short8;
typedef __attribute__((ext_vector_type(4))) float    f32x4;
typedef __attribute__((ext_vector_type(4))) unsigned uint4v;

#define FRAG0 256   // u32 offset of frag region in ws

__device__ __forceinline__ unsigned short f2bf(float f) {   // RNE
    unsigned u = __builtin_bit_cast(unsigned, f);
    u = u + 0x7fffu + ((u >> 16) & 1u);
    return (unsigned short)(u >> 16);
}
__device__ __forceinline__ unsigned packRNE(float hi, float lo) {
    return (unsigned)f2bf(lo) | ((unsigned)f2bf(hi) << 16);
}
__device__ __forceinline__ unsigned pack_trunc(float hi, float lo) {  // 1 v_perm
    return __builtin_amdgcn_perm(__builtin_bit_cast(unsigned, hi),
                                 __builtin_bit_cast(unsigned, lo), 0x07060302u);
}
__device__ __forceinline__ float rfl(float x) {
    return __builtin_bit_cast(float, __builtin_amdgcn_readfirstlane(__builtin_bit_cast(int, x)));
}
__device__ __forceinline__ f32x4 mfma16(short8 a, short8 b, f32x4 c) {
    return __builtin_amdgcn_mfma_f32_16x16x32_bf16(a, b, c, 0, 0, 0);
}
__device__ __forceinline__ unsigned bperm(int addr, unsigned v) {
    return (unsigned)__builtin_amdgcn_ds_bpermute(addr, (int)v);
}
__device__ __forceinline__ float swz1f(float v){ return __builtin_bit_cast(float, __builtin_amdgcn_ds_swizzle(__builtin_bit_cast(int, v), 0x041F)); }
__device__ __forceinline__ float swz2f(float v){ return __builtin_bit_cast(float, __builtin_amdgcn_ds_swizzle(__builtin_bit_cast(int, v), 0x081F)); }
__device__ __forceinline__ unsigned swz1u(unsigned v){ return (unsigned)__builtin_amdgcn_ds_swizzle((int)v, 0x041F); }
__device__ __forceinline__ float sigf(float x) { return __builtin_amdgcn_rcpf(1.f + __expf(-x)); }
__device__ __forceinline__ float tanhfast(float x) {
    float e = __expf(2.f * x);
    return 1.f - 2.f * __builtin_amdgcn_rcpf(e + 1.f);
}
__device__ __forceinline__ f32x4 ld4(const float* p) { return *(const f32x4*)p; }

__device__ __forceinline__ void packC(unsigned* P, f32x4 a0, f32x4 a1, bool oob) {
    float r0 = fmaxf(a0[0], 0.f), r1 = fmaxf(a0[1], 0.f), r2 = fmaxf(a0[2], 0.f), r3 = fmaxf(a0[3], 0.f);
    float s0 = fmaxf(a1[0], 0.f), s1 = fmaxf(a1[1], 0.f), s2 = fmaxf(a1[2], 0.f), s3 = fmaxf(a1[3], 0.f);
    P[0] = pack_trunc(r1, r0); P[1] = pack_trunc(r3, r2);
    P[2] = pack_trunc(s1, s0); P[3] = pack_trunc(s3, s2);
    if (oob) { P[0] = 0u; P[1] = 0u; P[2] = 0u; P[3] = 0u; }
}

// ===================== prep kernel: MLP compose + frag prepack =====================
__global__ __launch_bounds__(256) void r2p2_prep(
    const float* __restrict__ w0, const float* __restrict__ w1,
    const float* __restrict__ w2, const float* __restrict__ w3,
    const float* __restrict__ enc_whh,
    const float* __restrict__ dec_wih, const float* __restrict__ dec_whh,
    const float* __restrict__ mw1, const float* __restrict__ mb1,
    const float* __restrict__ mw2, const float* __restrict__ mb2,
    float* __restrict__ wsf, unsigned* __restrict__ wsu) {
    const int tid = threadIdx.x, bx = blockIdx.x;
    if (bx == 0) {
        // ---- composed MLP: M[4][32] + c[4], 2 threads per output, 4-acc ILP ----
        int o = tid >> 1, half = tid & 1;
        int j = o >> 5, k = o & 31;
        const float* w2r = mw2 + j * 512 + half * 256;
        const float* w1c = mw1 + half * 256 * 32 + k;
        float a0 = 0.f, a1 = 0.f, a2 = 0.f, a3 = 0.f;
#pragma unroll 4
        for (int m = 0; m < 256; m += 4) {
            a0 = fmaf(w2r[m],     w1c[m * 32],       a0);
            a1 = fmaf(w2r[m + 1], w1c[(m + 1) * 32], a1);
            a2 = fmaf(w2r[m + 2], w1c[(m + 2) * 32], a2);
            a3 = fmaf(w2r[m + 3], w1c[(m + 3) * 32], a3);
        }
        float acc = (a0 + a1) + (a2 + a3);
        float part = __shfl_xor(acc, 1, 64);
        if (half == 0) wsf[o] = acc + part;
        if (tid < 8) {
            int oc = tid >> 1, hc = tid & 1;
            const float* w2c = mw2 + oc * 512 + hc * 256;
            const float* b1c = mb1 + hc * 256;
            float c0 = 0.f, c1 = 0.f, c2 = 0.f, c3 = 0.f;
#pragma unroll 4
            for (int m = 0; m < 256; m += 4) {
                c0 = fmaf(w2c[m],     b1c[m],     c0);
                c1 = fmaf(w2c[m + 1], b1c[m + 1], c1);
                c2 = fmaf(w2c[m + 2], b1c[m + 2], c2);
                c3 = fmaf(w2c[m + 3], b1c[m + 3], c3);
            }
            float a2s = (c0 + c1) + (c2 + c3);
            float p2 = __shfl_xor(a2s, 1, 64);
            if (hc == 0) wsf[128 + oc] = a2s + p2 + mb2[oc];
        }
        return;
    }
    // ---- frag prepack: 44 frags x 64 lanes, cells split over blocks 1..7 ----
    int base = (bx - 1) * 416;
    for (int c = base + tid; c < base + 416 && c < 2816; c += 256) {
        int f = c >> 6, lane = c & 63;
        int n = lane & 15, q = lane >> 4;
        int pc0 = ((n >> 2) << 3) | (n & 3);
        float v[8];
        if (f < 2) {
            int co = pc0 + f * 4;
#pragma unroll
            for (int j = 0; j < 8; ++j) v[j] = (q == 0) ? w0[j * 32 + co] : 0.f;
        } else if (f < 26) {
            int t = f - 2;
            const float* W = (t < 8) ? w1 : (t < 16) ? w2 : w3;
            t &= 7;
            int mt = t >> 2, ks = t & 3, co = pc0 + mt * 4;
#pragma unroll
            for (int j = 0; j < 8; ++j) v[j] = W[(ks * 32 + q * 8 + j) * 32 + co];
        } else if (f < 32) {
            int t = f - 26, gate = t >> 1, mt = t & 1;
            int row = gate * 32 + pc0 + mt * 4;
#pragma unroll
            for (int j = 0; j < 8; ++j) v[j] = dec_wih[row * 34 + 2 + q * 8 + j];
        } else if (f < 38) {
            int t = f - 32, gate = t >> 1, mt = t & 1;
            int row = gate * 32 + pc0 + mt * 4;
#pragma unroll
            for (int j = 0; j < 8; ++j) v[j] = dec_whh[row * 32 + q * 8 + j];
        } else {
            int t = f - 38, gate = t >> 1, mt = t & 1;
            int row = gate * 32 + pc0 + mt * 4;
#pragma unroll
            for (int j = 0; j < 8; ++j) v[j] = enc_whh[row * 32 + q * 8 + j];
        }
        uint4v u;
        u[0] = packRNE(v[1], v[0]); u[1] = packRNE(v[3], v[2]);
        u[2] = packRNE(v[5], v[4]); u[3] = packRNE(v[7], v[6]);
        *(uint4v*)(wsu + FRAG0 + f * 256 + lane * 4) = u;
    }
}

// ===================== main kernel =====================
__global__ __launch_bounds__(256)
__attribute__((amdgpu_waves_per_eu(1, 1)))
void r2p2_main(
    const float* __restrict__ z, const float* __restrict__ past, const float* __restrict__ lidar,
    const float* __restrict__ b0, const float* __restrict__ b1,
    const float* __restrict__ b2, const float* __restrict__ b3,
    const float* __restrict__ enc_wih, const float* __restrict__ enc_bih, const float* __restrict__ enc_bhh,
    const float* __restrict__ dec_wih, const float* __restrict__ dec_bih, const float* __restrict__ dec_bhh,
    const float* __restrict__ wsf, const unsigned* __restrict__ wsu,
    float* __restrict__ out) {

    const int tid = threadIdx.x, b = blockIdx.x;
    const int wid = tid >> 6, lane = tid & 63;
    const int n = lane & 15, q = lane >> 4, e = n & 1;

    __shared__ __align__(16) unsigned sLID[104 * 104];
    __shared__ __align__(16) float PASTs[40];
    __shared__ __align__(16) float ZVs[64];

    if (wid != 0) {
        // ====== waves 1-3: lidar staging + z ======
        int st = tid - 64;   // 0..191
        if (st < 60) ZVs[st] = z[b * 60 + st];
        for (int i = st; i < 816; i += 192) {   // zero border
            int idx = (i < 416) ? (10400 + i) : ((((i - 416) >> 2) * 104) + 100 + ((i - 416) & 3));
            sLID[idx] = 0u;
        }
        const float4* lp4 = (const float4*)(lidar + (size_t)b * 20000);
#pragma unroll 4
        for (int i = st; i < 5000; i += 192) {
            int r = (int)(((unsigned)i * 5243u) >> 18);   // i / 50
            int c2 = i - r * 50;
            float4 v = lp4[i];
            int o = r * 104 + 2 * c2;
            sLID[o]     = pack_trunc(v.y, v.x);
            sLID[o + 1] = pack_trunc(v.w, v.z);
        }
        __syncthreads();
        return;
    }

    // ====== wave 0: coalesced frag loads (MUST stay register-resident) ======
    uint4v FR[44];
#pragma unroll
    for (int f = 0; f < 44; ++f) FR[f] = *(const uint4v*)(wsu + FRAG0 + f * 256 + lane * 4);
#define FRG(f) __builtin_bit_cast(short8, FR[f])

    // biases (contiguous ld4)
    f32x4 cb0[2], cb1[2], cb2[2], cb3[2], gbR[2], gbZ[2], gbNi[2], gbNh[2];
    f32x4 egR[2], egZ[2], egNh[2];
#pragma unroll
    for (int mt = 0; mt < 2; ++mt) {
        int o = q * 8 + mt * 4;
        cb0[mt] = ld4(b0 + o); cb1[mt] = ld4(b1 + o); cb2[mt] = ld4(b2 + o); cb3[mt] = ld4(b3 + o);
        gbR[mt]  = ld4(dec_bih + o)      + ld4(dec_bhh + o);
        gbZ[mt]  = ld4(dec_bih + 32 + o) + ld4(dec_bhh + 32 + o);
        gbNi[mt] = ld4(dec_bih + 64 + o);
        gbNh[mt] = ld4(dec_bhh + 64 + o);
        egR[mt]  = ld4(enc_bih + o)      + ld4(enc_bhh + o);
        egZ[mt]  = ld4(enc_bih + 32 + o) + ld4(enc_bhh + 32 + o);
        egNh[mt] = ld4(enc_bhh + 64 + o);
    }
    f32x4 ebni = ld4(enc_bih + 64 + q * 8 + e * 4);
    float2 wxr[4], wxz[4], wxn[4], wexr[4], wexz[4], wexn[4];
#pragma unroll
    for (int r = 0; r < 4; ++r) {
        int c = q * 8 + e * 4 + r;
        wxr[r]  = *(const float2*)(dec_wih + c * 34);
        wxz[r]  = *(const float2*)(dec_wih + (32 + c) * 34);
        wxn[r]  = *(const float2*)(dec_wih + (64 + c) * 34);
        wexr[r] = *(const float2*)(enc_wih + c * 2);
        wexz[r] = *(const float2*)(enc_wih + (32 + c) * 2);
        wexn[r] = *(const float2*)(enc_wih + (64 + c) * 2);
    }
    short8 Am = (short8)0;
    if (n < 4) {
#pragma unroll
        for (int j = 0; j < 8; ++j) Am[j] = (short)f2bf(wsf[n * 32 + q * 8 + j]);
    }
    f32x4 mcv = {0.f, 0.f, 0.f, 0.f};
    if (q == 0) mcv = *(const f32x4*)(wsf + 128);

    if (lane < 20) *(float2*)&PASTs[2 * lane] = *(const float2*)(past + b * 40 + 2 * lane);
    float q0 = past[b * 40 + 38], q1 = past[b * 40 + 39];
    float p0 = past[b * 40 + 36], p1 = past[b * 40 + 37];
    asm volatile("s_waitcnt lgkmcnt(0)" ::: "memory");

    // ====== encoder: register GRU, 20 steps ======
    float hq[4] = {0.f, 0.f, 0.f, 0.f};
    short8 hfr = (short8)0;
#pragma unroll 1
    for (int t = 0; t < 20; ++t) {
        float2 xp = *(const float2*)&PASTs[2 * t];
        f32x4 gr0 = mfma16(FRG(38), hfr, egR[0]),  gr1 = mfma16(FRG(39), hfr, egR[1]);
        f32x4 gz0 = mfma16(FRG(40), hfr, egZ[0]),  gz1 = mfma16(FRG(41), hfr, egZ[1]);
        f32x4 gh0 = mfma16(FRG(42), hfr, egNh[0]), gh1 = mfma16(FRG(43), hfr, egNh[1]);
        f32x4 grS = e ? gr1 : gr0, gzS = e ? gz1 : gz0, ghS = e ? gh1 : gh0;
        float hn[4];
#pragma unroll
        for (int r = 0; r < 4; ++r) {
            float rp = grS[r] + xp.x * wexr[r].x + xp.y * wexr[r].y;
            float zp = gzS[r] + xp.x * wexz[r].x + xp.y * wexz[r].y;
            float pi = ebni[r] + xp.x * wexn[r].x + xp.y * wexn[r].y;
            float rr = sigf(rp), zz = sigf(zp);
            float tn = tanhfast(fmaf(rr, ghS[r], pi));
            float hv = tn + zz * (hq[r] - tn);
            hq[r] = hv; hn[r] = hv;
        }
        unsigned hu0 = packRNE(hn[1], hn[0]), hu1 = packRNE(hn[3], hn[2]);
        unsigned po0 = swz1u(hu0), po1 = swz1u(hu1);
        uint4v hv4;
        hv4[0] = e ? po0 : hu0; hv4[1] = e ? po1 : hu1;
        hv4[2] = e ? hu0 : po0; hv4[3] = e ? hu1 : po1;
        hfr = __builtin_bit_cast(short8, hv4);
    }

    __syncthreads();   // join staging waves

    // hoisted geometry
    int py0a = n / 5, px0a = n % 5;
    int pe0b = (16 + n < 25) ? 16 + n : 24;
    int py0b = pe0b / 5, px0b = pe0b - py0b * 5;
    int ofs0a[4], ofs0b[4];
#pragma unroll
    for (int tp = 0; tp < 4; ++tp) {
        ofs0a[tp] = (py0a + (tp >> 1)) * 104 + px0a + (tp & 1);
        ofs0b[tp] = (py0b + (tp >> 1)) * 104 + px0b + (tp & 1);
    }
    int py1 = n >> 2, px1 = n & 3;
    int adr1[4], sel1m[4];
#pragma unroll
    for (int ks = 0; ks < 4; ++ks) {
        int p = (py1 + (ks >> 1)) * 5 + px1 + (ks & 1);
        adr1[ks] = (q * 16 + (p & 15)) * 4;
        sel1m[ks] = (p >= 16);
    }
    int pe2 = (n < 9) ? n : 8, py2 = pe2 / 3, px2 = pe2 - py2 * 3;
    int adr2[4];
#pragma unroll
    for (int ks = 0; ks < 4; ++ks) adr2[ks] = (q * 16 + (py2 + (ks >> 1)) * 4 + px2 + (ks & 1)) * 4;
    int pe3 = n & 3, py3 = pe3 >> 1, px3 = pe3 & 1;
    int adr3[4];
#pragma unroll
    for (int ks = 0; ks < 4; ++ks) adr3[ks] = (q * 16 + (py3 + (ks >> 1)) * 3 + px3 + (ks & 1)) * 4;
    const f32x4 zf4 = {0.f, 0.f, 0.f, 0.f};
    float la = 0.f;

#pragma unroll 1
    for (int t = 0; t < 30; ++t) {
        float2 zv = *(const float2*)&ZVs[2 * t];   // hoisted off the tail chain
        float f0 = fminf(fmaxf(floorf(q0), 0.f), 98.f);
        float f1v = fminf(fmaxf(floorf(q1), 0.f), 98.f);
        int fy = (int)f0, fx = (int)f1v;
        float ay = fminf(fmaxf(q0 - f0, 0.f), 1.f);
        float ax = fminf(fmaxf(q1 - f1v, 0.f), 1.f);
        int base = fy * 104 + fx;
        int limy = 100 - fy, limx = 100 - fx;

        // ---- conv0 ----
        short8 bfa = (short8)0, bfb = (short8)0;
        if (q == 0) {
            uint4v ua, ub;
#pragma unroll
            for (int tp = 0; tp < 4; ++tp) { ua[tp] = sLID[base + ofs0a[tp]]; ub[tp] = sLID[base + ofs0b[tp]]; }
            bfa = __builtin_bit_cast(short8, ua);
            bfb = __builtin_bit_cast(short8, ub);
        }
        f32x4 ca0 = mfma16(FRG(0), bfa, cb0[0]);
        f32x4 ca1 = mfma16(FRG(1), bfa, cb0[1]);
        f32x4 cB0 = mfma16(FRG(0), bfb, cb0[0]);
        f32x4 cB1 = mfma16(FRG(1), bfb, cb0[1]);
        unsigned Pa[4], Pb[4];
        packC(Pa, ca0, ca1, (py0a >= limy) || (px0a >= limx));
        packC(Pb, cB0, cB1, (py0b >= limy) || (px0b >= limx));

        // ---- conv1 ----
        short8 bf1[4];
#pragma unroll
        for (int ks = 0; ks < 4; ++ks) {
            uint4v bu;
#pragma unroll
            for (int u = 0; u < 4; ++u) {
                unsigned va = bperm(adr1[ks], Pa[u]);
                unsigned vb = bperm(adr1[ks], Pb[u]);
                bu[u] = sel1m[ks] ? vb : va;
            }
            bf1[ks] = __builtin_bit_cast(short8, bu);
        }
        {
            f32x4 aA = mfma16(FRG(2), bf1[0], cb1[0]); aA = mfma16(FRG(3), bf1[1], aA);
            f32x4 aB = mfma16(FRG(4), bf1[2], zf4);    aB = mfma16(FRG(5), bf1[3], aB);
            f32x4 bA = mfma16(FRG(6), bf1[0], cb1[1]); bA = mfma16(FRG(7), bf1[1], bA);
            f32x4 bB = mfma16(FRG(8), bf1[2], zf4);    bB = mfma16(FRG(9), bf1[3], bB);
            f32x4 o0 = aA + aB, o1 = bA + bB;
            packC(Pa, o0, o1, (py1 >= limy) || (px1 >= limx));
        }

        // ---- conv2 ----
        short8 bf2v[4];
#pragma unroll
        for (int ks = 0; ks < 4; ++ks) {
            uint4v bu;
#pragma unroll
            for (int u = 0; u < 4; ++u) bu[u] = bperm(adr2[ks], Pa[u]);
            bf2v[ks] = __builtin_bit_cast(short8, bu);
        }
        {
            f32x4 aA = mfma16(FRG(10), bf2v[0], cb2[0]); aA = mfma16(FRG(11), bf2v[1], aA);
            f32x4 aB = mfma16(FRG(12), bf2v[2], zf4);    aB = mfma16(FRG(13), bf2v[3], aB);
            f32x4 bA = mfma16(FRG(14), bf2v[0], cb2[1]); bA = mfma16(FRG(15), bf2v[1], bA);
            f32x4 bB = mfma16(FRG(16), bf2v[2], zf4);    bB = mfma16(FRG(17), bf2v[3], bB);
            f32x4 o0 = aA + aB, o1 = bA + bB;
            packC(Pb, o0, o1, (py2 >= limy) || (px2 >= limx));
        }

        // ---- conv3 + bilinear butterfly ----
        short8 bf3v[4];
#pragma unroll
        for (int ks = 0; ks < 4; ++ks) {
            uint4v bu;
#pragma unroll
            for (int u = 0; u < 4; ++u) bu[u] = bperm(adr3[ks], Pb[u]);
            bf3v[ks] = __builtin_bit_cast(short8, bu);
        }
        short8 xf;
        {
            f32x4 aA = mfma16(FRG(18), bf3v[0], cb3[0]); aA = mfma16(FRG(19), bf3v[1], aA);
            f32x4 aB = mfma16(FRG(20), bf3v[2], zf4);    aB = mfma16(FRG(21), bf3v[3], aB);
            f32x4 bA = mfma16(FRG(22), bf3v[0], cb3[1]); bA = mfma16(FRG(23), bf3v[1], bA);
            f32x4 bB = mfma16(FRG(24), bf3v[2], zf4);    bB = mfma16(FRG(25), bf3v[3], bB);
            f32x4 o0 = aA + aB, o1 = bA + bB;
            float wy = (n & 2) ? ay : 1.f - ay;
            float wx = (n & 1) ? ax : 1.f - ax;
            float w = wy * wx;
            float t0[4], t1[4];
#pragma unroll
            for (int r = 0; r < 4; ++r) { t0[r] = fmaxf(o0[r], 0.f) * w; t1[r] = fmaxf(o1[r], 0.f) * w; }
#pragma unroll
            for (int r = 0; r < 4; ++r) { t0[r] += swz1f(t0[r]); t1[r] += swz1f(t1[r]); }
#pragma unroll
            for (int r = 0; r < 4; ++r) { t0[r] += swz2f(t0[r]); t1[r] += swz2f(t1[r]); }
            uint4v xu;
            xu[0] = packRNE(t0[1], t0[0]); xu[1] = packRNE(t0[3], t0[2]);
            xu[2] = packRNE(t1[1], t1[0]); xu[3] = packRNE(t1[3], t1[2]);
            xf = __builtin_bit_cast(short8, xu);
        }

        // ---- decoder GRU ----
        f32x4 gr0 = mfma16(FRG(26), xf, gbR[0]); gr0 = mfma16(FRG(32), hfr, gr0);
        f32x4 gr1 = mfma16(FRG(27), xf, gbR[1]); gr1 = mfma16(FRG(33), hfr, gr1);
        f32x4 gz0 = mfma16(FRG(28), xf, gbZ[0]); gz0 = mfma16(FRG(34), hfr, gz0);
        f32x4 gz1 = mfma16(FRG(29), xf, gbZ[1]); gz1 = mfma16(FRG(35), hfr, gz1);
        f32x4 gi0 = mfma16(FRG(30), xf, gbNi[0]);
        f32x4 gi1 = mfma16(FRG(31), xf, gbNi[1]);
        f32x4 gh0 = mfma16(FRG(36), hfr, gbNh[0]);
        f32x4 gh1 = mfma16(FRG(37), hfr, gbNh[1]);
        f32x4 grS = e ? gr1 : gr0, gzS = e ? gz1 : gz0, giS = e ? gi1 : gi0, ghS = e ? gh1 : gh0;
        float hn[4];
#pragma unroll
        for (int r = 0; r < 4; ++r) {
            float rp = grS[r] + q0 * wxr[r].x + q1 * wxr[r].y;
            float zp = gzS[r] + q0 * wxz[r].x + q1 * wxz[r].y;
            float pi = giS[r] + q0 * wxn[r].x + q1 * wxn[r].y;
            float rr = sigf(rp), zz = sigf(zp);
            float tn = tanhfast(fmaf(rr, ghS[r], pi));
            float hv = tn + zz * (hq[r] - tn);
            hq[r] = hv; hn[r] = hv;
        }
        unsigned hu0 = packRNE(hn[1], hn[0]), hu1 = packRNE(hn[3], hn[2]);
        unsigned po0 = swz1u(hu0), po1 = swz1u(hu1);
        uint4v hv4;
        hv4[0] = e ? po0 : hu0; hv4[1] = e ? po1 : hu1;
        hv4[2] = e ? hu0 : po0; hv4[3] = e ? hu1 : po1;
        hfr = __builtin_bit_cast(short8, hv4);

        // ---- head + tail ----
        f32x4 ls = mfma16(Am, hfr, mcv);
        float l2 = ls[2], l3 = ls[3];
        float s0 = fmaxf(l2, 0.f) + __logf(1.f + __expf(-fabsf(l2)));
        float s1 = fmaxf(l3, 0.f) + __logf(1.f + __expf(-fabsf(l3)));
        float ny0 = 2.f * q0 - p0 + ls[0] + s0 * zv.x;
        float ny1 = 2.f * q1 - p1 + ls[1] + s1 * zv.y;
        if (lane == 0) {
            float2 o2 = {ny0, ny1};
            *(float2*)(out + b * 60 + 2 * t) = o2;
        }
        la += __logf(s0 * s1);
        p0 = q0; p1 = q1;
        q0 = rfl(ny0); q1 = rfl(ny1);
    }
    if (lane == 0) out[15360 + b] = la;
#undef FRG
}

extern "C" void kernel_launch(void* const* d_in, const int* in_sizes, int n_in,
                              void* d_out, int out_size, void* d_ws, size_t ws_size,
                              hipStream_t stream) {
    const float* z    = (const float*)d_in[0];
    const float* past = (const float*)d_in[1];
    const float* lid  = (const float*)d_in[2];
    const float* c0w = (const float*)d_in[3];  const float* c0b = (const float*)d_in[4];
    const float* c1w = (const float*)d_in[5];  const float* c1b = (const float*)d_in[6];
    const float* c2w = (const float*)d_in[7];  const float* c2b = (const float*)d_in[8];
    const float* c3w = (const float*)d_in[9];  const float* c3b = (const float*)d_in[10];
    const float* ewih = (const float*)d_in[11]; const float* ewhh = (const float*)d_in[12];
    const float* ebih = (const float*)d_in[13]; const float* ebhh = (const float*)d_in[14];
    const float* dwih = (const float*)d_in[15]; const float* dwhh = (const float*)d_in[16];
    const float* dbih = (const float*)d_in[17]; const float* dbhh = (const float*)d_in[18];
    const float* mw1 = (const float*)d_in[19]; const float* mb1 = (const float*)d_in[20];
    const float* mw2 = (const float*)d_in[21]; const float* mb2 = (const float*)d_in[22];
    float* out = (float*)d_out;
    float* wsf = (float*)d_ws;
    unsigned* wsu = (unsigned*)d_ws;

    r2p2_prep<<<8, 256, 0, stream>>>(c0w, c1w, c2w, c3w, ewhh, dwih, dwhh,
                                     mw1, mb1, mw2, mb2, wsf, wsu);
    r2p2_main<<<256, 256, 0, stream>>>(z, past, lid, c0b, c1b, c2b, c3b,
                                       ewih, ebih, ebhh, dwih, dbih, dbhh,
                                       wsf, wsu, out);
}

// Round 8
// 182.987 us; speedup vs baseline: 1.8024x; 1.0089x over previous
//
#include <hip/hip_runtime.h>
#include <math.h>

typedef __attribute__((ext_vector_type(8))) short    short8;
typedef __attribute__((ext_vector_type(4))) float    f32x4;
typedef __attribute__((ext_vector_type(4))) unsigned uint4v;

#define FRAG0 256   // u32 offset of frag region in ws

__device__ __forceinline__ unsigned short f2bf(float f) {   // RNE
    unsigned u = __builtin_bit_cast(unsigned, f);
    u = u + 0x7fffu + ((u >> 16) & 1u);
    return (unsigned short)(u >> 16);
}
__device__ __forceinline__ unsigned packRNE(float hi, float lo) {
    return (unsigned)f2bf(lo) | ((unsigned)f2bf(hi) << 16);
}
__device__ __forceinline__ unsigned pack_trunc(float hi, float lo) {  // 1 v_perm
    return __builtin_amdgcn_perm(__builtin_bit_cast(unsigned, hi),
                                 __builtin_bit_cast(unsigned, lo), 0x07060302u);
}
__device__ __forceinline__ float rfl(float x) {
    return __builtin_bit_cast(float, __builtin_amdgcn_readfirstlane(__builtin_bit_cast(int, x)));
}
__device__ __forceinline__ f32x4 mfma16(short8 a, short8 b, f32x4 c) {
    return __builtin_amdgcn_mfma_f32_16x16x32_bf16(a, b, c, 0, 0, 0);
}
__device__ __forceinline__ unsigned bperm(int addr, unsigned v) {
    return (unsigned)__builtin_amdgcn_ds_bpermute(addr, (int)v);
}
template<int PAT>
__device__ __forceinline__ float swzXf(float v) {
    return __builtin_bit_cast(float, __builtin_amdgcn_ds_swizzle(__builtin_bit_cast(int, v), PAT));
}
__device__ __forceinline__ unsigned swz1u(unsigned v){ return (unsigned)__builtin_amdgcn_ds_swizzle((int)v, 0x041F); }
__device__ __forceinline__ float sigf(float x) { return __builtin_amdgcn_rcpf(1.f + __expf(-x)); }
__device__ __forceinline__ float tanhfast(float x) {
    float e = __expf(2.f * x);
    return 1.f - 2.f * __builtin_amdgcn_rcpf(e + 1.f);
}
__device__ __forceinline__ f32x4 ld4(const float* p) { return *(const f32x4*)p; }

__device__ __forceinline__ void packC(unsigned* P, f32x4 a0, f32x4 a1, bool oob) {
    float r0 = fmaxf(a0[0], 0.f), r1 = fmaxf(a0[1], 0.f), r2 = fmaxf(a0[2], 0.f), r3 = fmaxf(a0[3], 0.f);
    float s0 = fmaxf(a1[0], 0.f), s1 = fmaxf(a1[1], 0.f), s2 = fmaxf(a1[2], 0.f), s3 = fmaxf(a1[3], 0.f);
    P[0] = pack_trunc(r1, r0); P[1] = pack_trunc(r3, r2);
    P[2] = pack_trunc(s1, s0); P[3] = pack_trunc(s3, s2);
    if (oob) { P[0] = 0u; P[1] = 0u; P[2] = 0u; P[3] = 0u; }
}

// ===================== prep kernel: MLP compose + frag prepack =====================
__global__ __launch_bounds__(256) void r2p2_prep(
    const float* __restrict__ w0, const float* __restrict__ w1,
    const float* __restrict__ w2, const float* __restrict__ w3,
    const float* __restrict__ enc_whh,
    const float* __restrict__ dec_wih, const float* __restrict__ dec_whh,
    const float* __restrict__ mw1, const float* __restrict__ mb1,
    const float* __restrict__ mw2, const float* __restrict__ mb2,
    float* __restrict__ wsf, unsigned* __restrict__ wsu) {
    const int tid = threadIdx.x, bx = blockIdx.x;
    if (bx == 0) {
        // ---- composed MLP, coalesced: threads 0..127 -> M[j][k]; 128..191 -> c partials ----
        __shared__ float red[64];
        if (tid < 128) {
            int k = tid & 31, j = tid >> 5;
            const float* w2r = mw2 + j * 512;
            float a0 = 0.f, a1 = 0.f, a2 = 0.f, a3 = 0.f;
#pragma unroll 4
            for (int m = 0; m < 512; m += 4) {
                a0 = fmaf(w2r[m],     mw1[m * 32 + k],       a0);
                a1 = fmaf(w2r[m + 1], mw1[(m + 1) * 32 + k], a1);
                a2 = fmaf(w2r[m + 2], mw1[(m + 2) * 32 + k], a2);
                a3 = fmaf(w2r[m + 3], mw1[(m + 3) * 32 + k], a3);
            }
            wsf[j * 32 + k] = (a0 + a1) + (a2 + a3);
        } else if (tid < 192) {
            int t = tid - 128;          // 0..63: j = t&3, chunk = t>>2 (16 chunks of 32)
            int j = t & 3, ch = t >> 2;
            const float* w2c = mw2 + j * 512 + ch * 32;
            const float* b1c = mb1 + ch * 32;
            float p = 0.f;
#pragma unroll 8
            for (int m = 0; m < 32; ++m) p = fmaf(w2c[m], b1c[m], p);
            red[t] = p;
        }
        __syncthreads();
        if (tid < 4) {
            float c = mb2[tid];
#pragma unroll
            for (int i = 0; i < 16; ++i) c += red[tid + i * 4];
            wsf[128 + tid] = c;
        }
        return;
    }
    // ---- frag prepack: 44 frags x 64 lanes, cells split over blocks 1..7 ----
    int base = (bx - 1) * 416;
    for (int c = base + tid; c < base + 416 && c < 2816; c += 256) {
        int f = c >> 6, lane = c & 63;
        int n = lane & 15, q = lane >> 4;
        int pc0 = ((n >> 2) << 3) | (n & 3);
        float v[8];
        if (f < 2) {
            int co = pc0 + f * 4;
#pragma unroll
            for (int j = 0; j < 8; ++j) v[j] = (q == 0) ? w0[j * 32 + co] : 0.f;
        } else if (f < 26) {
            int t = f - 2;
            const float* W = (t < 8) ? w1 : (t < 16) ? w2 : w3;
            t &= 7;
            int mt = t >> 2, ks = t & 3, co = pc0 + mt * 4;
#pragma unroll
            for (int j = 0; j < 8; ++j) v[j] = W[(ks * 32 + q * 8 + j) * 32 + co];
        } else if (f < 32) {
            int t = f - 26, gate = t >> 1, mt = t & 1;
            int row = gate * 32 + pc0 + mt * 4;
#pragma unroll
            for (int j = 0; j < 8; ++j) v[j] = dec_wih[row * 34 + 2 + q * 8 + j];
        } else if (f < 38) {
            int t = f - 32, gate = t >> 1, mt = t & 1;
            int row = gate * 32 + pc0 + mt * 4;
#pragma unroll
            for (int j = 0; j < 8; ++j) v[j] = dec_whh[row * 32 + q * 8 + j];
        } else {
            int t = f - 38, gate = t >> 1, mt = t & 1;
            int row = gate * 32 + pc0 + mt * 4;
#pragma unroll
            for (int j = 0; j < 8; ++j) v[j] = enc_whh[row * 32 + q * 8 + j];
        }
        uint4v u;
        u[0] = packRNE(v[1], v[0]); u[1] = packRNE(v[3], v[2]);
        u[2] = packRNE(v[5], v[4]); u[3] = packRNE(v[7], v[6]);
        *(uint4v*)(wsu + FRAG0 + f * 256 + lane * 4) = u;
    }
}

// ===================== main kernel =====================
__global__ __launch_bounds__(256)
void r2p2_main(
    const float* __restrict__ z, const float* __restrict__ past, const float* __restrict__ lidar,
    const float* __restrict__ b0, const float* __restrict__ b1,
    const float* __restrict__ b2, const float* __restrict__ b3,
    const float* __restrict__ enc_wih, const float* __restrict__ enc_bih, const float* __restrict__ enc_bhh,
    const float* __restrict__ dec_wih, const float* __restrict__ dec_bih, const float* __restrict__ dec_bhh,
    const float* __restrict__ wsf, const unsigned* __restrict__ wsu,
    float* __restrict__ out) {

    const int tid = threadIdx.x, b = blockIdx.x;
    const int wid = tid >> 6, lane = tid & 63;
    const int n = lane & 15, q = lane >> 4, e = n & 1;

    __shared__ __align__(16) unsigned sLID[104 * 104];
    __shared__ __align__(16) float PASTs[40];
    __shared__ __align__(16) float ZVs[64];

    if (wid != 0) {
        // ====== waves 1-3: lidar staging + z ======
        int st = tid - 64;   // 0..191
        if (st < 60) ZVs[st] = z[b * 60 + st];
        for (int i = st; i < 816; i += 192) {   // zero border
            int idx = (i < 416) ? (10400 + i) : ((((i - 416) >> 2) * 104) + 100 + ((i - 416) & 3));
            sLID[idx] = 0u;
        }
        const float4* lp4 = (const float4*)(lidar + (size_t)b * 20000);
#pragma unroll 4
        for (int i = st; i < 5000; i += 192) {
            int r = (int)(((unsigned)i * 5243u) >> 18);   // i / 50
            int c2 = i - r * 50;
            float4 v = lp4[i];
            int o = r * 104 + 2 * c2;
            sLID[o]     = pack_trunc(v.y, v.x);
            sLID[o + 1] = pack_trunc(v.w, v.z);
        }
        __syncthreads();
        return;
    }

    // ====== wave 0: coalesced frag loads ======
    uint4v FR[44];
#pragma unroll
    for (int f = 0; f < 44; ++f) FR[f] = *(const uint4v*)(wsu + FRAG0 + f * 256 + lane * 4);
#define FRG(f) __builtin_bit_cast(short8, FR[f])

    // biases (contiguous ld4)
    f32x4 cb0[2], cb1[2], cb2[2], cb3[2], gbR[2], gbZ[2], gbNi[2], gbNh[2];
    f32x4 egR[2], egZ[2], egNh[2];
#pragma unroll
    for (int mt = 0; mt < 2; ++mt) {
        int o = q * 8 + mt * 4;
        cb0[mt] = ld4(b0 + o); cb1[mt] = ld4(b1 + o); cb2[mt] = ld4(b2 + o); cb3[mt] = ld4(b3 + o);
        gbR[mt]  = ld4(dec_bih + o)      + ld4(dec_bhh + o);
        gbZ[mt]  = ld4(dec_bih + 32 + o) + ld4(dec_bhh + 32 + o);
        gbNi[mt] = ld4(dec_bih + 64 + o);
        gbNh[mt] = ld4(dec_bhh + 64 + o);
        egR[mt]  = ld4(enc_bih + o)      + ld4(enc_bhh + o);
        egZ[mt]  = ld4(enc_bih + 32 + o) + ld4(enc_bhh + 32 + o);
        egNh[mt] = ld4(enc_bhh + 64 + o);
    }
    f32x4 ebni = ld4(enc_bih + 64 + q * 8 + e * 4);
    float2 wxr[4], wxz[4], wxn[4], wexr[4], wexz[4], wexn[4];
#pragma unroll
    for (int r = 0; r < 4; ++r) {
        int c = q * 8 + e * 4 + r;
        wxr[r]  = *(const float2*)(dec_wih + c * 34);
        wxz[r]  = *(const float2*)(dec_wih + (32 + c) * 34);
        wxn[r]  = *(const float2*)(dec_wih + (64 + c) * 34);
        wexr[r] = *(const float2*)(enc_wih + c * 2);
        wexz[r] = *(const float2*)(enc_wih + (32 + c) * 2);
        wexn[r] = *(const float2*)(enc_wih + (64 + c) * 2);
    }
    short8 Am = (short8)0;
    if (n < 4) {
#pragma unroll
        for (int j = 0; j < 8; ++j) Am[j] = (short)f2bf(wsf[n * 32 + q * 8 + j]);
    }
    f32x4 mcv = {0.f, 0.f, 0.f, 0.f};
    if (q == 0) mcv = *(const f32x4*)(wsf + 128);

    if (lane < 20) *(float2*)&PASTs[2 * lane] = *(const float2*)(past + b * 40 + 2 * lane);
    float q0 = past[b * 40 + 38], q1 = past[b * 40 + 39];
    float p0 = past[b * 40 + 36], p1 = past[b * 40 + 37];
    asm volatile("s_waitcnt lgkmcnt(0)" ::: "memory");

    // ====== encoder: register GRU, 20 steps ======
    float hq[4] = {0.f, 0.f, 0.f, 0.f};
    short8 hfr = (short8)0;
#pragma unroll 1
    for (int t = 0; t < 20; ++t) {
        float2 xp = *(const float2*)&PASTs[2 * t];
        f32x4 gr0 = mfma16(FRG(38), hfr, egR[0]),  gr1 = mfma16(FRG(39), hfr, egR[1]);
        f32x4 gz0 = mfma16(FRG(40), hfr, egZ[0]),  gz1 = mfma16(FRG(41), hfr, egZ[1]);
        f32x4 gh0 = mfma16(FRG(42), hfr, egNh[0]), gh1 = mfma16(FRG(43), hfr, egNh[1]);
        f32x4 grS = e ? gr1 : gr0, gzS = e ? gz1 : gz0, ghS = e ? gh1 : gh0;
        float hn[4];
#pragma unroll
        for (int r = 0; r < 4; ++r) {
            float rp = grS[r] + xp.x * wexr[r].x + xp.y * wexr[r].y;
            float zp = gzS[r] + xp.x * wexz[r].x + xp.y * wexz[r].y;
            float pi = ebni[r] + xp.x * wexn[r].x + xp.y * wexn[r].y;
            float rr = sigf(rp), zz = sigf(zp);
            float tn = tanhfast(fmaf(rr, ghS[r], pi));
            float hv = tn + zz * (hq[r] - tn);
            hq[r] = hv; hn[r] = hv;
        }
        unsigned hu0 = packRNE(hn[1], hn[0]), hu1 = packRNE(hn[3], hn[2]);
        unsigned po0 = swz1u(hu0), po1 = swz1u(hu1);
        uint4v hv4;
        hv4[0] = e ? po0 : hu0; hv4[1] = e ? po1 : hu1;
        hv4[2] = e ? hu0 : po0; hv4[3] = e ? hu1 : po1;
        hfr = __builtin_bit_cast(short8, hv4);
    }

    __syncthreads();   // join staging waves

    // hoisted geometry
    int py0a = n / 5, px0a = n % 5;
    int pe0b = (16 + n < 25) ? 16 + n : 24;
    int py0b = pe0b / 5, px0b = pe0b - py0b * 5;
    int ofs0a[4], ofs0b[4];
#pragma unroll
    for (int tp = 0; tp < 4; ++tp) {
        ofs0a[tp] = (py0a + (tp >> 1)) * 104 + px0a + (tp & 1);
        ofs0b[tp] = (py0b + (tp >> 1)) * 104 + px0b + (tp & 1);
    }
    int py1 = n >> 2, px1 = n & 3;
    int adr1[4], sel1m[4];
#pragma unroll
    for (int ks = 0; ks < 4; ++ks) {
        int p = (py1 + (ks >> 1)) * 5 + px1 + (ks & 1);
        adr1[ks] = (q * 16 + (p & 15)) * 4;
        sel1m[ks] = (p >= 16);
    }
    int pe2 = (n < 9) ? n : 8, py2 = pe2 / 3, px2 = pe2 - py2 * 3;
    int adr2[4];
#pragma unroll
    for (int ks = 0; ks < 4; ++ks) adr2[ks] = (q * 16 + (py2 + (ks >> 1)) * 4 + px2 + (ks & 1)) * 4;
    int pe3 = n & 3, py3 = pe3 >> 1, px3 = pe3 & 1;
    int adr3[4];
#pragma unroll
    for (int ks = 0; ks < 4; ++ks) adr3[ks] = (q * 16 + (py3 + (ks >> 1)) * 3 + px3 + (ks & 1)) * 4;
    const f32x4 zf4 = {0.f, 0.f, 0.f, 0.f};
    float la = 0.f;

#pragma unroll 1
    for (int t = 0; t < 30; ++t) {
        float2 zv = *(const float2*)&ZVs[2 * t];
        float f0 = fminf(fmaxf(floorf(q0), 0.f), 98.f);
        float f1v = fminf(fmaxf(floorf(q1), 0.f), 98.f);
        int fy = (int)f0, fx = (int)f1v;
        float ay = fminf(fmaxf(q0 - f0, 0.f), 1.f);
        float ax = fminf(fmaxf(q1 - f1v, 0.f), 1.f);
        int base = fy * 104 + fx;
        int limy = 100 - fy, limx = 100 - fx;

        // ---- conv0 ----
        short8 bfa = (short8)0, bfb = (short8)0;
        if (q == 0) {
            uint4v ua, ub;
#pragma unroll
            for (int tp = 0; tp < 4; ++tp) { ua[tp] = sLID[base + ofs0a[tp]]; ub[tp] = sLID[base + ofs0b[tp]]; }
            bfa = __builtin_bit_cast(short8, ua);
            bfb = __builtin_bit_cast(short8, ub);
        }
        f32x4 ca0 = mfma16(FRG(0), bfa, cb0[0]);
        f32x4 ca1 = mfma16(FRG(1), bfa, cb0[1]);
        f32x4 cB0 = mfma16(FRG(0), bfb, cb0[0]);
        f32x4 cB1 = mfma16(FRG(1), bfb, cb0[1]);
        unsigned Pa[4], Pb[4];
        packC(Pa, ca0, ca1, (py0a >= limy) || (px0a >= limx));
        packC(Pb, cB0, cB1, (py0b >= limy) || (px0b >= limx));

        // ---- conv1 ----
        short8 bf1[4];
#pragma unroll
        for (int ks = 0; ks < 4; ++ks) {
            uint4v bu;
#pragma unroll
            for (int u = 0; u < 4; ++u) {
                unsigned va = bperm(adr1[ks], Pa[u]);
                unsigned vb = bperm(adr1[ks], Pb[u]);
                bu[u] = sel1m[ks] ? vb : va;
            }
            bf1[ks] = __builtin_bit_cast(short8, bu);
        }
        {
            f32x4 aA = mfma16(FRG(2), bf1[0], cb1[0]); aA = mfma16(FRG(3), bf1[1], aA);
            f32x4 aB = mfma16(FRG(4), bf1[2], zf4);    aB = mfma16(FRG(5), bf1[3], aB);
            f32x4 bA = mfma16(FRG(6), bf1[0], cb1[1]); bA = mfma16(FRG(7), bf1[1], bA);
            f32x4 bB = mfma16(FRG(8), bf1[2], zf4);    bB = mfma16(FRG(9), bf1[3], bB);
            f32x4 o0 = aA + aB, o1 = bA + bB;
            packC(Pa, o0, o1, (py1 >= limy) || (px1 >= limx));
        }

        // ---- conv2 ----
        short8 bf2v[4];
#pragma unroll
        for (int ks = 0; ks < 4; ++ks) {
            uint4v bu;
#pragma unroll
            for (int u = 0; u < 4; ++u) bu[u] = bperm(adr2[ks], Pa[u]);
            bf2v[ks] = __builtin_bit_cast(short8, bu);
        }
        {
            f32x4 aA = mfma16(FRG(10), bf2v[0], cb2[0]); aA = mfma16(FRG(11), bf2v[1], aA);
            f32x4 aB = mfma16(FRG(12), bf2v[2], zf4);    aB = mfma16(FRG(13), bf2v[3], aB);
            f32x4 bA = mfma16(FRG(14), bf2v[0], cb2[1]); bA = mfma16(FRG(15), bf2v[1], bA);
            f32x4 bB = mfma16(FRG(16), bf2v[2], zf4);    bB = mfma16(FRG(17), bf2v[3], bB);
            f32x4 o0 = aA + aB, o1 = bA + bB;
            packC(Pb, o0, o1, (py2 >= limy) || (px2 >= limx));
        }

        // ---- conv3 + bilinear (single DS round: 3 parallel swizzles) ----
        short8 bf3v[4];
#pragma unroll
        for (int ks = 0; ks < 4; ++ks) {
            uint4v bu;
#pragma unroll
            for (int u = 0; u < 4; ++u) bu[u] = bperm(adr3[ks], Pb[u]);
            bf3v[ks] = __builtin_bit_cast(short8, bu);
        }
        short8 xf;
        {
            f32x4 aA = mfma16(FRG(18), bf3v[0], cb3[0]); aA = mfma16(FRG(19), bf3v[1], aA);
            f32x4 aB = mfma16(FRG(20), bf3v[2], zf4);    aB = mfma16(FRG(21), bf3v[3], aB);
            f32x4 bA = mfma16(FRG(22), bf3v[0], cb3[1]); bA = mfma16(FRG(23), bf3v[1], bA);
            f32x4 bB = mfma16(FRG(24), bf3v[2], zf4);    bB = mfma16(FRG(25), bf3v[3], bB);
            f32x4 o0 = aA + aB, o1 = bA + bB;
            float wy = (n & 2) ? ay : 1.f - ay;
            float wx = (n & 1) ? ax : 1.f - ax;
            float w = wy * wx;
            float t0[4], t1[4];
#pragma unroll
            for (int r = 0; r < 4; ++r) { t0[r] = fmaxf(o0[r], 0.f) * w; t1[r] = fmaxf(o1[r], 0.f) * w; }
#pragma unroll
            for (int r = 0; r < 4; ++r) {
                float a1 = swzXf<0x041F>(t0[r]), a2 = swzXf<0x081F>(t0[r]), a3 = swzXf<0x0C1F>(t0[r]);
                t0[r] = (t0[r] + a1) + (a2 + a3);
                float b1v = swzXf<0x041F>(t1[r]), b2v = swzXf<0x081F>(t1[r]), b3v = swzXf<0x0C1F>(t1[r]);
                t1[r] = (t1[r] + b1v) + (b2v + b3v);
            }
            uint4v xu;
            xu[0] = packRNE(t0[1], t0[0]); xu[1] = packRNE(t0[3], t0[2]);
            xu[2] = packRNE(t1[1], t1[0]); xu[3] = packRNE(t1[3], t1[2]);
            xf = __builtin_bit_cast(short8, xu);
        }

        // ---- decoder GRU ----
        f32x4 gr0 = mfma16(FRG(26), xf, gbR[0]); gr0 = mfma16(FRG(32), hfr, gr0);
        f32x4 gr1 = mfma16(FRG(27), xf, gbR[1]); gr1 = mfma16(FRG(33), hfr, gr1);
        f32x4 gz0 = mfma16(FRG(28), xf, gbZ[0]); gz0 = mfma16(FRG(34), hfr, gz0);
        f32x4 gz1 = mfma16(FRG(29), xf, gbZ[1]); gz1 = mfma16(FRG(35), hfr, gz1);
        f32x4 gi0 = mfma16(FRG(30), xf, gbNi[0]);
        f32x4 gi1 = mfma16(FRG(31), xf, gbNi[1]);
        f32x4 gh0 = mfma16(FRG(36), hfr, gbNh[0]);
        f32x4 gh1 = mfma16(FRG(37), hfr, gbNh[1]);
        f32x4 grS = e ? gr1 : gr0, gzS = e ? gz1 : gz0, giS = e ? gi1 : gi0, ghS = e ? gh1 : gh0;
        float hn[4];
#pragma unroll
        for (int r = 0; r < 4; ++r) {
            float rp = grS[r] + q0 * wxr[r].x + q1 * wxr[r].y;
            float zp = gzS[r] + q0 * wxz[r].x + q1 * wxz[r].y;
            float pi = giS[r] + q0 * wxn[r].x + q1 * wxn[r].y;
            float rr = sigf(rp), zz = sigf(zp);
            float tn = tanhfast(fmaf(rr, ghS[r], pi));
            float hv = tn + zz * (hq[r] - tn);
            hq[r] = hv; hn[r] = hv;
        }
        unsigned hu0 = packRNE(hn[1], hn[0]), hu1 = packRNE(hn[3], hn[2]);
        unsigned po0 = swz1u(hu0), po1 = swz1u(hu1);
        uint4v hv4;
        hv4[0] = e ? po0 : hu0; hv4[1] = e ? po1 : hu1;
        hv4[2] = e ? hu0 : po0; hv4[3] = e ? hu1 : po1;
        hfr = __builtin_bit_cast(short8, hv4);

        // ---- head + tail ----
        f32x4 ls = mfma16(Am, hfr, mcv);
        float l2 = ls[2], l3 = ls[3];
        float s0 = fmaxf(l2, 0.f) + __logf(1.f + __expf(-fabsf(l2)));
        float s1 = fmaxf(l3, 0.f) + __logf(1.f + __expf(-fabsf(l3)));
        float ny0 = 2.f * q0 - p0 + ls[0] + s0 * zv.x;
        float ny1 = 2.f * q1 - p1 + ls[1] + s1 * zv.y;
        if (lane == 0) {
            float2 o2 = {ny0, ny1};
            *(float2*)(out + b * 60 + 2 * t) = o2;
        }
        la += __logf(s0 * s1);
        p0 = q0; p1 = q1;
        q0 = rfl(ny0); q1 = rfl(ny1);
    }
    if (lane == 0) out[15360 + b] = la;
#undef FRG
}

extern "C" void kernel_launch(void* const* d_in, const int* in_sizes, int n_in,
                              void* d_out, int out_size, void* d_ws, size_t ws_size,
                              hipStream_t stream) {
    const float* z    = (const float*)d_in[0];
    const float* past = (const float*)d_in[1];
    const float* lid  = (const float*)d_in[2];
    const float* c0w = (const float*)d_in[3];  const float* c0b = (const float*)d_in[4];
    const float* c1w = (const float*)d_in[5];  const float* c1b = (const float*)d_in[6];
    const float* c2w = (const float*)d_in[7];  const float* c2b = (const float*)d_in[8];
    const float* c3w = (const float*)d_in[9];  const float* c3b = (const float*)d_in[10];
    const float* ewih = (const float*)d_in[11]; const float* ewhh = (const float*)d_in[12];
    const float* ebih = (const float*)d_in[13]; const float* ebhh = (const float*)d_in[14];
    const float* dwih = (const float*)d_in[15]; const float* dwhh = (const float*)d_in[16];
    const float* dbih = (const float*)d_in[17]; const float* dbhh = (const float*)d_in[18];
    const float* mw1 = (const float*)d_in[19]; const float* mb1 = (const float*)d_in[20];
    const float* mw2 = (const float*)d_in[21]; const float* mb2 = (const float*)d_in[22];
    float* out = (float*)d_out;
    float* wsf = (float*)d_ws;
    unsigned* wsu = (unsigned*)d_ws;

    r2p2_prep<<<8, 256, 0, stream>>>(c0w, c1w, c2w, c3w, ewhh, dwih, dwhh,
                                     mw1, mb1, mw2, mb2, wsf, wsu);
    r2p2_main<<<256, 256, 0, stream>>>(z, past, lid, c0b, c1b, c2b, c3b,
                                       ewih, ebih, ebhh, dwih, dbih, dbhh,
                                       wsf, wsu, out);
}